// Round 5
// baseline (961.477 us; speedup 1.0000x reference)
//
#include <hip/hip_runtime.h>
#include <hip/hip_bf16.h>

typedef __attribute__((ext_vector_type(8))) short short8;
typedef __attribute__((ext_vector_type(4))) short short4v;
typedef __attribute__((ext_vector_type(4))) float floatx4;
typedef __hip_bfloat16 bf16;

#define M1 1048576L  // 1024*1024
#define MB (1024L * 1024L)

__device__ __forceinline__ void async16(const short* g, short* l) {
  __builtin_amdgcn_global_load_lds((const __attribute__((address_space(1))) void*)g,
                                   (__attribute__((address_space(3))) void*)l, 16, 0, 0);
}

// ===================== 256x256 8-wave BK=64 core (r11) =======================
// r9 measured: MfmaUtil 27.7%, VALUBusy 11.8%, conflicts 0 -> lockstep
// LDS-read/MFMA ping-pong (192KB reads vs 620cy MFMA per tile = 27% ceiling).
// r11: m201-style 4-sub-phase interleave per K-tile: each phase
// {ds_read cluster; barrier; lgkmcnt(0); setprio(1); 16 MFMA; setprio(0);
//  barrier}. Tile-start keeps bulk stage + counted vmcnt(8) (loads are a full
// tile old when waited on). Quadrant order (L,0),(L,1),(H,1),(H,0) reuses
// fragments across adjacent phases (24 ds_read_b128/wave/tile total).
#define LDS256 16384  // shorts per (buffer x matrix)

__device__ __forceinline__ void gemm256_loop(const short* A, const short* B, int K,
    int lda, int ldb, short* sA, short* sB, int m0, int n0, floatx4 (&acc)[8][4]) {
  const int tid = threadIdx.x, wave = tid >> 6, lane = tid & 63;
  const int lane15 = lane & 15, quad = lane >> 4;
  const int wm = wave & 1, wn = wave >> 1;
  // staging: thread tid covers 16B chunk (tid&7) of row (tid>>3); stored chunk
  // slot p holds logical kchunk p^(row&7) -> pre-swizzled global src (rule #21)
  const int r0t = tid >> 3;                         // 0..63
  const int ksw = ((tid & 7) ^ (r0t & 7)) * 8;      // shorts
  const short* aS = A + (long)(m0 + r0t) * lda + ksw;
  const short* bS = B + (long)(n0 + r0t) * ldb + ksw;
  short* ldA = sA + tid * 8;
  short* ldB = sB + tid * 8;
  // read-side: frag (mt,kk) lane l: row = base + mt*16 + (l&15),
  // kchunk = kk*4 + quad, stored at slot chunk^(row&7) = chunk^(l&7)
  const int pos0 = (quad ^ (lane15 & 7)) * 8;       // shorts, kk=0
  const int aOff = (wm * 128 + lane15) * 64 + pos0;
  const int bOff = (wn * 64 + lane15) * 64 + pos0;  // kk=1: XOR 32 shorts

#pragma unroll
  for (int i = 0; i < 8; i++)
#pragma unroll
    for (int j = 0; j < 4; j++) { floatx4 zz = {0.f, 0.f, 0.f, 0.f}; acc[i][j] = zz; }

  auto stage = [&](int bi, long kOff) {
#pragma unroll
    for (int j = 0; j < 4; ++j)
      async16(aS + kOff + (long)j * 64 * lda, ldA + bi * LDS256 + j * 4096);
#pragma unroll
    for (int j = 0; j < 4; ++j)
      async16(bS + kOff + (long)j * 64 * ldb, ldB + bi * LDS256 + j * 4096);
  };

  stage(0, 0);
  const int NT = K >> 6;
  for (int t = 0; t < NT; ++t) {
    const int bi = t & 1;
    if (t + 1 < NT) {
      stage(bi ^ 1, (long)(t + 1) * 64);
      // wait for tile t's 8 loads (issued a full tile ago); t+1's 8 stay in
      // flight across the barrier (T4: never drain fresh loads).
      asm volatile("s_waitcnt vmcnt(8)" ::: "memory");
    } else {
      asm volatile("s_waitcnt vmcnt(0)" ::: "memory");
    }
    __builtin_amdgcn_s_barrier();       // tile-t data ready for all waves
    __builtin_amdgcn_sched_barrier(0);
    const short* aB = sA + bi * LDS256;
    const short* bB = sB + bi * LDS256;
    short8 faL[4][2], faH[4][2], fb0[2][2], fb1[2][2];
    // ---- P0: read A-low(8) + B-low(4); MFMA quadrant (m-low, n-low)
#pragma unroll
    for (int mh = 0; mh < 4; ++mh)
#pragma unroll
      for (int kk = 0; kk < 2; ++kk)
        faL[mh][kk] = *(const short8*)(aB + ((aOff + mh * 1024) ^ (kk * 32)));
#pragma unroll
    for (int nn = 0; nn < 2; ++nn)
#pragma unroll
      for (int kk = 0; kk < 2; ++kk)
        fb0[nn][kk] = *(const short8*)(bB + ((bOff + nn * 1024) ^ (kk * 32)));
    __builtin_amdgcn_s_barrier();
    asm volatile("s_waitcnt lgkmcnt(0)" ::: "memory");
    __builtin_amdgcn_sched_barrier(0);
    __builtin_amdgcn_s_setprio(1);
#pragma unroll
    for (int mh = 0; mh < 4; ++mh)
#pragma unroll
      for (int nn = 0; nn < 2; ++nn)
#pragma unroll
        for (int kk = 0; kk < 2; ++kk)
          acc[mh][nn] = __builtin_amdgcn_mfma_f32_16x16x32_bf16(faL[mh][kk], fb0[nn][kk], acc[mh][nn], 0, 0, 0);
    __builtin_amdgcn_s_setprio(0);
    __builtin_amdgcn_s_barrier();
    // ---- P1: read B-high(4); MFMA (m-low, n-high)
#pragma unroll
    for (int nn = 0; nn < 2; ++nn)
#pragma unroll
      for (int kk = 0; kk < 2; ++kk)
        fb1[nn][kk] = *(const short8*)(bB + ((bOff + (2 + nn) * 1024) ^ (kk * 32)));
    __builtin_amdgcn_s_barrier();
    asm volatile("s_waitcnt lgkmcnt(0)" ::: "memory");
    __builtin_amdgcn_sched_barrier(0);
    __builtin_amdgcn_s_setprio(1);
#pragma unroll
    for (int mh = 0; mh < 4; ++mh)
#pragma unroll
      for (int nn = 0; nn < 2; ++nn)
#pragma unroll
        for (int kk = 0; kk < 2; ++kk)
          acc[mh][2 + nn] = __builtin_amdgcn_mfma_f32_16x16x32_bf16(faL[mh][kk], fb1[nn][kk], acc[mh][2 + nn], 0, 0, 0);
    __builtin_amdgcn_s_setprio(0);
    __builtin_amdgcn_s_barrier();
    // ---- P2: read A-high(8); MFMA (m-high, n-high)
#pragma unroll
    for (int mh = 0; mh < 4; ++mh)
#pragma unroll
      for (int kk = 0; kk < 2; ++kk)
        faH[mh][kk] = *(const short8*)(aB + ((aOff + (4 + mh) * 1024) ^ (kk * 32)));
    __builtin_amdgcn_s_barrier();
    asm volatile("s_waitcnt lgkmcnt(0)" ::: "memory");
    __builtin_amdgcn_sched_barrier(0);
    __builtin_amdgcn_s_setprio(1);
#pragma unroll
    for (int mh = 0; mh < 4; ++mh)
#pragma unroll
      for (int nn = 0; nn < 2; ++nn)
#pragma unroll
        for (int kk = 0; kk < 2; ++kk)
          acc[4 + mh][2 + nn] = __builtin_amdgcn_mfma_f32_16x16x32_bf16(faH[mh][kk], fb1[nn][kk], acc[4 + mh][2 + nn], 0, 0, 0);
    __builtin_amdgcn_s_setprio(0);
    __builtin_amdgcn_s_barrier();       // all reads of buf bi retired here
    // ---- P3: no reads; MFMA (m-high, n-low) -- faH, fb0 live in regs
    __builtin_amdgcn_s_setprio(1);
#pragma unroll
    for (int mh = 0; mh < 4; ++mh)
#pragma unroll
      for (int nn = 0; nn < 2; ++nn)
#pragma unroll
        for (int kk = 0; kk < 2; ++kk)
          acc[4 + mh][nn] = __builtin_amdgcn_mfma_f32_16x16x32_bf16(faH[mh][kk], fb0[nn][kk], acc[4 + mh][nn], 0, 0, 0);
    __builtin_amdgcn_s_setprio(0);
    // next tile's stage targets buf bi^1 (write-safe: this tile read only bi)
  }
}

// flags: 1=C^T  2=f32  4=RMW accumulate (f32 C^T)  32=grid xy swapped
__device__ __forceinline__ void epi256(void* C, const float* bias, long cOff,
    int ldc, int fl, int m0, int n0, floatx4 (&acc)[8][4]) {
  const int lane = threadIdx.x & 63, wave = threadIdx.x >> 6;
  const int lane15 = lane & 15, quad = lane >> 4;
  const int wm = wave & 1, wn = wave >> 1;
#pragma unroll
  for (int mt = 0; mt < 8; mt++)
#pragma unroll
    for (int nt = 0; nt < 4; nt++) {
      const int mg = m0 + wm * 128 + mt * 16 + quad * 4;
      const int ng = n0 + wn * 64 + nt * 16 + lane15;
      floatx4 v = acc[mt][nt];
      if (bias) {
        v.x += bias[mg + 0]; v.y += bias[mg + 1];
        v.z += bias[mg + 2]; v.w += bias[mg + 3];
      }
      if (fl & 1) {  // C^T: [N][ldc]
        const long o = cOff + (long)ng * ldc + mg;
        if (fl & 2) {
          float* cp = (float*)C + o;
          if (fl & 4) { v.x += cp[0]; v.y += cp[1]; v.z += cp[2]; v.w += cp[3]; }
          cp[0] = v.x; cp[1] = v.y; cp[2] = v.z; cp[3] = v.w;
        } else {
          bf16* cp = (bf16*)C + o;
          cp[0] = __float2bfloat16(v.x); cp[1] = __float2bfloat16(v.y);
          cp[2] = __float2bfloat16(v.z); cp[3] = __float2bfloat16(v.w);
        }
      } else {       // plain C: [M][ldc]
        const long o = cOff + (long)mg * ldc + ng;
        if (fl & 2) {
          float* cp = (float*)C + o;
          cp[0] = v.x; cp[ldc] = v.y; cp[2L * ldc] = v.z; cp[3L * ldc] = v.w;
        } else {
          bf16* cp = (bf16*)C + o;
          cp[0] = __float2bfloat16(v.x); cp[ldc] = __float2bfloat16(v.y);
          cp[2L * ldc] = __float2bfloat16(v.z); cp[3L * ldc] = __float2bfloat16(v.w);
        }
      }
    }
}

// ------------------------------------------------- generic strided-z GEMM ---
struct GemmP {
  const short* A; const short* B; void* C; const float* bias;
  long sA1, sA2, sB1, sB2, sC1, sC2, sb1, sb2;
  int M, N, K, lda, ldb, ldc, Z2, flags;
};

__global__ __launch_bounds__(512, 2) void gemm256_kernel(GemmP p) {
  __shared__ __align__(16) short sA[2 * LDS256];
  __shared__ __align__(16) short sB[2 * LDS256];
  const int z = blockIdx.z, z1 = z / p.Z2, z2 = z % p.Z2;
  const short* A = p.A + z1 * p.sA1 + z2 * p.sA2;
  const short* B = p.B + z1 * p.sB1 + z2 * p.sB2;
  const long cOff = z1 * p.sC1 + z2 * p.sC2;
  const float* bias = p.bias;
  if (bias) bias += z1 * p.sb1 + z2 * p.sb2;
  int m0, n0;
  if (p.flags & 32) { m0 = blockIdx.x * 256; n0 = blockIdx.y * 256; }
  else              { m0 = blockIdx.y * 256; n0 = blockIdx.x * 256; }
  floatx4 acc[8][4];
  gemm256_loop(A, B, p.K, p.lda, p.ldb, sA, sB, m0, n0, acc);
  epi256(p.C, bias, cOff, p.ldc, p.flags, m0, n0, acc);
}

// -------------------------------- 4-way batched GEMM (proj / QKV [+O]) ------
struct QkvP {
  const short* W[4]; const short* F[4]; void* C[4]; const float* bias[4];
  int fl[4], Kd[4], ld[4];
};

__global__ __launch_bounds__(512, 2) void qkv256_kernel(QkvP q) {
  __shared__ __align__(16) short sA[2 * LDS256];
  __shared__ __align__(16) short sB[2 * LDS256];
  const int z = blockIdx.z, w = z >> 2, b = z & 3;
  const int K = q.Kd[w], ld = q.ld[w];
  const short* A = q.W[w];
  const short* B = q.F[w] + (long)b * 1024 * K;
  floatx4 acc[8][4];
  gemm256_loop(A, B, K, ld, ld, sA, sB, blockIdx.y * 256, blockIdx.x * 256, acc);
  epi256(q.C[w], q.bias[w], (long)b * M1, 1024, q.fl[w], blockIdx.y * 256, blockIdx.x * 256, acc);
}

// ===================== 128x128 4-wave core (PV + O-conv) =====================
__device__ __forceinline__ void gemm_loop(const short* A, const short* B, int K,
    int lda, int ldb, short* sA, short* sB, int m0, int n0, floatx4 (&acc)[4][4]) {
  const int tid = threadIdx.x, wave = tid >> 6, lane = tid & 63;
  const int lane15 = lane & 15, quad = lane >> 4;
  const int mW = (wave & 1) * 64, nW = (wave >> 1) * 64;
  const int row4 = lane >> 2;
  const int kcol = ((lane & 3) ^ ((row4 >> 1) & 3)) * 8;  // swizzled fetch quad
  const int psw = (lane15 >> 1) & 3;                       // read-side swizzle
  const short* aP0 = A + (long)(m0 + wave * 32 + row4) * lda + kcol;
  const short* aP1 = aP0 + (long)16 * lda;
  const short* bP0 = B + (long)(n0 + wave * 32 + row4) * ldb + kcol;
  const short* bP1 = bP0 + (long)16 * ldb;
  short* sAw = sA + wave * 1024;
  short* sBw = sB + wave * 1024;
  const short* rA = sA + (mW + lane15) * 32 + (quad ^ psw) * 8;
  const short* rB = sB + (nW + lane15) * 32 + (quad ^ psw) * 8;
#pragma unroll
  for (int i = 0; i < 4; i++)
#pragma unroll
    for (int j = 0; j < 4; j++) { floatx4 zz = {0.f, 0.f, 0.f, 0.f}; acc[i][j] = zz; }

  async16(aP0, sAw); async16(aP1, sAw + 512);
  async16(bP0, sBw); async16(bP1, sBw + 512);
  aP0 += 32; aP1 += 32; bP0 += 32; bP1 += 32;
  asm volatile("s_waitcnt vmcnt(0)" ::: "memory");
  __builtin_amdgcn_s_barrier();

  int cur = 0;
  const int NT = K >> 5;
  for (int t = 0; t < NT - 1; ++t) {
    const int nxt = cur ^ 4096;
    async16(aP0, sAw + nxt); async16(aP1, sAw + nxt + 512);
    async16(bP0, sBw + nxt); async16(bP1, sBw + nxt + 512);
    aP0 += 32; aP1 += 32; bP0 += 32; bP1 += 32;
    short8 af[4], bfr[4];
#pragma unroll
    for (int mt = 0; mt < 4; mt++) af[mt] = *(const short8*)(rA + cur + mt * 512);
#pragma unroll
    for (int nt = 0; nt < 4; nt++) bfr[nt] = *(const short8*)(rB + cur + nt * 512);
#pragma unroll
    for (int mt = 0; mt < 4; mt++)
#pragma unroll
      for (int nt = 0; nt < 4; nt++)
        acc[mt][nt] = __builtin_amdgcn_mfma_f32_16x16x32_bf16(af[mt], bfr[nt], acc[mt][nt], 0, 0, 0);
    asm volatile("s_waitcnt vmcnt(0)" ::: "memory");
    __builtin_amdgcn_s_barrier();
    cur = nxt;
  }
  {
    short8 af[4], bfr[4];
#pragma unroll
    for (int mt = 0; mt < 4; mt++) af[mt] = *(const short8*)(rA + cur + mt * 512);
#pragma unroll
    for (int nt = 0; nt < 4; nt++) bfr[nt] = *(const short8*)(rB + cur + nt * 512);
#pragma unroll
    for (int mt = 0; mt < 4; mt++)
#pragma unroll
      for (int nt = 0; nt < 4; nt++)
        acc[mt][nt] = __builtin_amdgcn_mfma_f32_16x16x32_bf16(af[mt], bfr[nt], acc[mt][nt], 0, 0, 0);
  }
}

__device__ __forceinline__ void gemm_epi(void* C, const float* bias, long cOff,
    int ldc, int fl, int m0, int n0, floatx4 (&acc)[4][4]) {
  const int lane = threadIdx.x & 63, wave = threadIdx.x >> 6;
  const int lane15 = lane & 15, quad = lane >> 4;
  const int mW = (wave & 1) * 64, nW = (wave >> 1) * 64;
#pragma unroll
  for (int mt = 0; mt < 4; mt++)
#pragma unroll
    for (int nt = 0; nt < 4; nt++) {
      const int mg = m0 + mW + mt * 16 + quad * 4;
      const int ng = n0 + nW + nt * 16 + lane15;
      floatx4 v = acc[mt][nt];
      if (bias) {
        v.x += bias[mg + 0]; v.y += bias[mg + 1];
        v.z += bias[mg + 2]; v.w += bias[mg + 3];
      }
      if (fl & 1) {
        const long o = cOff + (long)ng * ldc + mg;
        if (fl & 2) {
          float* cp = (float*)C + o;
          if (fl & 4) { v.x += cp[0]; v.y += cp[1]; v.z += cp[2]; v.w += cp[3]; }
          cp[0] = v.x; cp[1] = v.y; cp[2] = v.z; cp[3] = v.w;
        } else {
          bf16* cp = (bf16*)C + o;
          cp[0] = __float2bfloat16(v.x); cp[1] = __float2bfloat16(v.y);
          cp[2] = __float2bfloat16(v.z); cp[3] = __float2bfloat16(v.w);
        }
      } else {
        const long o = cOff + (long)mg * ldc + ng;
        if (fl & 2) {
          float* cp = (float*)C + o;
          cp[0] = v.x; cp[ldc] = v.y; cp[2L * ldc] = v.z; cp[3L * ldc] = v.w;
        } else {
          bf16* cp = (bf16*)C + o;
          cp[0] = __float2bfloat16(v.x); cp[ldc] = __float2bfloat16(v.y);
          cp[2L * ldc] = __float2bfloat16(v.z); cp[3L * ldc] = __float2bfloat16(v.w);
        }
      }
    }
}

__global__ __launch_bounds__(256) void gemm_kernel(GemmP p) {
  __shared__ __align__(16) short sA[8192];
  __shared__ __align__(16) short sB[8192];
  const int z = blockIdx.z, z1 = z / p.Z2, z2 = z % p.Z2;
  const short* A = p.A + z1 * p.sA1 + z2 * p.sA2;
  const short* B = p.B + z1 * p.sB1 + z2 * p.sB2;
  const long cOff = z1 * p.sC1 + z2 * p.sC2;
  const float* bias = p.bias;
  if (bias) bias += z1 * p.sb1 + z2 * p.sb2;
  int m0, n0;
  if (p.flags & 32) { m0 = blockIdx.x * 128; n0 = blockIdx.y * 128; }
  else              { m0 = blockIdx.y * 128; n0 = blockIdx.x * 128; }
  floatx4 acc[4][4];
  gemm_loop(A, B, p.K, p.lda, p.ldb, sA, sB, m0, n0, acc);
  gemm_epi(p.C, bias, cOff, p.ldc, p.flags, m0, n0, acc);
}

// ------------------- fused scores + softmax, 32-row blocks ------------------
__global__ __launch_bounds__(256) void attn_sm_k(const short* Q, const short* Kt, bf16* P) {
  __shared__ __align__(16) short sA[1024];
  __shared__ __align__(16) short sB[4096];
  __shared__ short S16[32 * 132];
  const int z = blockIdx.x, b = z >> 3, h = z & 7;
  const int r0 = blockIdx.y * 32;
  const int tid = threadIdx.x, wave = tid >> 6, lane = tid & 63;
  const int lane15 = lane & 15, quad = lane >> 4;
  const int row4 = lane >> 2;
  const int kcol = ((lane & 3) ^ ((row4 >> 1) & 3)) * 8;
  const int psw = (lane15 >> 1) & 3;
  const short* Ab = Q + (long)b * M1 + (long)h * 131072;
  const short* Bb = Kt + (long)b * M1 + (long)h * 131072;
  const short* aP = Ab + (long)(r0 + (wave & 1) * 16 + row4) * 1024 + kcol;
  const short* bP0 = Bb + (long)(wave * 32 + row4) * 1024 + kcol;
  const short* bP1 = bP0 + (long)16 * 1024;
  short* sBw = sB + wave * 1024;
  const short* rA = sA + lane15 * 32 + (quad ^ psw) * 8;
  const short* rB = sB + (wave * 32 + lane15) * 32 + (quad ^ psw) * 8;
  floatx4 acc[2][2];
#pragma unroll
  for (int i = 0; i < 2; i++)
#pragma unroll
    for (int j = 0; j < 2; j++) { floatx4 zz = {0.f, 0.f, 0.f, 0.f}; acc[i][j] = zz; }
  for (int k0 = 0; k0 < 1024; k0 += 32) {
    __syncthreads();
    if (wave < 2) async16(aP, sA + wave * 512);
    async16(bP0, sBw); async16(bP1, sBw + 512);
    aP += 32; bP0 += 32; bP1 += 32;
    __syncthreads();
    short8 af[2], bfr[2];
    af[0] = *(const short8*)(rA);
    af[1] = *(const short8*)(rA + 512);
    bfr[0] = *(const short8*)(rB);
    bfr[1] = *(const short8*)(rB + 512);
#pragma unroll
    for (int mt = 0; mt < 2; mt++)
#pragma unroll
      for (int nt = 0; nt < 2; nt++)
        acc[mt][nt] = __builtin_amdgcn_mfma_f32_16x16x32_bf16(af[mt], bfr[nt], acc[mt][nt], 0, 0, 0);
  }
  const float sc = 0.08838834764831845f;   // 128^-0.5
#pragma unroll
  for (int mt = 0; mt < 2; mt++)
#pragma unroll
    for (int nt = 0; nt < 2; nt++) {
      const int mg = mt * 16 + quad * 4, ng = wave * 32 + nt * 16 + lane15;
      floatx4 v = acc[mt][nt];
      *(bf16*)&S16[(mg + 0) * 132 + ng] = __float2bfloat16(v.x * sc);
      *(bf16*)&S16[(mg + 1) * 132 + ng] = __float2bfloat16(v.y * sc);
      *(bf16*)&S16[(mg + 2) * 132 + ng] = __float2bfloat16(v.z * sc);
      *(bf16*)&S16[(mg + 3) * 132 + ng] = __float2bfloat16(v.w * sc);
    }
  __syncthreads();
  bf16* Pb = P + (long)z * 16384 + (long)r0 * 128;
#pragma unroll
  for (int j = 0; j < 8; j++) {
    const int r = wave * 8 + j;
    float a = __bfloat162float(*(bf16*)&S16[r * 132 + lane]);
    float c = __bfloat162float(*(bf16*)&S16[r * 132 + lane + 64]);
    float m = fmaxf(a, c);
    for (int off = 32; off; off >>= 1) m = fmaxf(m, __shfl_xor(m, off));
    float e0 = expf(a - m), e1 = expf(c - m), s = e0 + e1;
    for (int off = 32; off; off >>= 1) s += __shfl_xor(s, off);
    const float inv = 1.0f / s;
    Pb[r * 128 + lane] = __float2bfloat16(e0 * inv);
    Pb[r * 128 + lane + 64] = __float2bfloat16(e1 * inv);
  }
}

// -------------------------------------------------------- f32 -> bf16 -------
__global__ void cvt_k(const float* src, bf16* dst, long n) {
  long i = ((long)blockIdx.x * 256 + threadIdx.x) * 4;
  if (i + 3 < n) {
    float4 v = *(const float4*)(src + i);
    bf16 t[4] = {__float2bfloat16(v.x), __float2bfloat16(v.y),
                 __float2bfloat16(v.z), __float2bfloat16(v.w)};
    *(short4v*)(dst + i) = *(short4v*)t;
  }
}

struct Cvt4 { const float* s[4]; bf16* d[4]; long n[4]; };
__global__ void cvt4_k(Cvt4 c) {
  const int seg = blockIdx.y;
  long i = ((long)blockIdx.x * 256 + threadIdx.x) * 4;
  if (i + 3 < c.n[seg]) {
    float4 v = *(const float4*)(c.s[seg] + i);
    bf16 t[4] = {__float2bfloat16(v.x), __float2bfloat16(v.y),
                 __float2bfloat16(v.z), __float2bfloat16(v.w)};
    *(short4v*)(c.d[seg] + i) = *(short4v*)t;
  }
}

// ------------------------------------------------------------ transpose -----
__global__ void trans_k(const float* in, bf16* out, int C, int D) {
  __shared__ float tile[32][33];
  const int d0 = blockIdx.x * 32, c0 = blockIdx.y * 32, b = blockIdx.z;
  const float* ib = in + (long)b * C * D;
  bf16* ob = out + (long)b * C * D;
  for (int i = threadIdx.y; i < 32; i += 8)
    tile[i][threadIdx.x] = ib[(long)(c0 + i) * D + d0 + threadIdx.x];
  __syncthreads();
  for (int i = threadIdx.y; i < 32; i += 8)
    ob[(long)(d0 + i) * C + c0 + threadIdx.x] = __float2bfloat16(tile[threadIdx.x][i]);
}

// ------------------------------------------------------ l2norm + metrics ----
__global__ __launch_bounds__(256) void norm_k(float* cross, bf16* feat, float* metrics) {
  const int blk = blockIdx.x;     // mod*4096 + pix
  const int mod = blk >> 12;
  float* base = cross + (long)blk * 1024;
  bf16* fb = feat + (long)blk * 1024;
  const int t = threadIdx.x;
  float v[4]; float ssq = 0.f;
#pragma unroll
  for (int j = 0; j < 4; j++) { v[j] = base[t + j * 256]; ssq += v[j] * v[j]; }
  __shared__ float r1[256], r2[256], r3[256];
  __shared__ float sinv;
  r1[t] = ssq; __syncthreads();
  for (int s = 128; s > 0; s >>= 1) { if (t < s) r1[t] += r1[t + s]; __syncthreads(); }
  if (t == 0) sinv = 1.0f / fmaxf(sqrtf(r1[0]), 1e-12f);
  __syncthreads();
  const float invn = sinv;
  float s1 = 0.f, s2 = 0.f, zc = 0.f;
#pragma unroll
  for (int j = 0; j < 4; j++) {
    float x = v[j] * invn; v[j] = x;
    s1 += x; s2 += x * x; if (x == 0.0f) zc += 1.0f;
  }
  r1[t] = s1; r2[t] = s2; r3[t] = zc; __syncthreads();
  for (int s = 128; s > 0; s >>= 1) {
    if (t < s) { r1[t] += r1[t + s]; r2[t] += r2[t + s]; r3[t] += r3[t + s]; }
    __syncthreads();
  }
  if (t == 0) {
    float m = (mod == 0) ? (r2[0] - r1[0] * r1[0] * (1.0f / 1024.f)) * (1.0f / 1023.f)
                         : r3[0] * (1.0f / 1024.f);
    metrics[blk] = m;
  }
#pragma unroll
  for (int j = 0; j < 4; j++) { base[t + j * 256] = v[j]; fb[t + j * 256] = __float2bfloat16(v[j]); }
}

// ----------------------------------------------------------------- SE -------
__global__ void zero_k(float* p, int n) {
  int i = blockIdx.x * 256 + threadIdx.x;
  if (i < n) p[i] = 0.f;
}

__global__ void pool_k(const float* cross, float* pooled) {
  const int blk = blockIdx.x;          // mb*16 + seg, mb = mod*4+b
  const int seg = blk & 15, mb = blk >> 4;
  const float* base = cross + (long)mb * M1 + (long)seg * 64 * 1024;
  float* pout = pooled + (long)mb * 1024;
  for (int c = threadIdx.x; c < 1024; c += 256) {
    float s = 0.f;
    for (int d = 0; d < 64; d++) s += base[(long)d * 1024 + c];
    atomicAdd(&pout[c], s * (1.0f / 1024.0f));
  }
}

__global__ void se_k(const float* pooled, const float* w1, const float* b1,
                     const float* w2, const float* b2, float* gvec) {
  const int mb = blockIdx.x, mod = mb >> 2, t = threadIdx.x;
  __shared__ float ps[1024]; __shared__ float hs[64];
  const float* p = pooled + (long)mb * 1024;
  for (int c = t; c < 1024; c += 256) ps[c] = p[c];
  __syncthreads();
  if (t < 64) {
    const float* wr = w1 + (long)(mod * 64 + t) * 1024;
    float s = 0.f;
    for (int c = 0; c < 1024; c++) s += wr[c] * ps[c];
    s += b1[mod * 64 + t];
    hs[t] = fmaxf(s, 0.f);
  }
  __syncthreads();
  for (int o = t; o < 1024; o += 256) {
    const float* wr = w2 + (long)(mod * 1024 + o) * 64;
    float s = 0.f;
    for (int j = 0; j < 64; j++) s += wr[j] * hs[j];
    s += b2[mod * 1024 + o];
    gvec[(long)mb * 1024 + o] = 1.0f / (1.0f + expf(-s));
  }
}

// ------------------------------------------------------- gates + fused ------
__global__ __launch_bounds__(256) void gatefuse_k(const float* cross, const float* gvec,
    const float* metrics, const float* gw, const float* gb, bf16* fused) {
  const int pix = blockIdx.x;          // b*1024 + d
  const int b = pix >> 10, t = threadIdx.x;
  __shared__ float refbuf[3072];
  __shared__ float red[3][256];
  __shared__ float gsh[3];
  float p0 = 0.f, p1 = 0.f, p2 = 0.f;
  for (int mod = 0; mod < 3; mod++) {
    const float* cb = cross + ((long)mod * 4096 + pix) * 1024;
    const float* gv = gvec + (long)(mod * 4 + b) * 1024;
    for (int c = t; c < 1024; c += 256) {
      float val = cb[c] * gv[c];
      refbuf[mod * 1024 + c] = val;
      p0 += gw[0 * 3075 + mod * 1024 + c] * val;
      p1 += gw[1 * 3075 + mod * 1024 + c] * val;
      p2 += gw[2 * 3075 + mod * 1024 + c] * val;
    }
  }
  red[0][t] = p0; red[1][t] = p1; red[2][t] = p2; __syncthreads();
  for (int s = 128; s > 0; s >>= 1) {
    if (t < s) { red[0][t] += red[0][t + s]; red[1][t] += red[1][t + s]; red[2][t] += red[2][t + s]; }
    __syncthreads();
  }
  if (t == 0) {
    const float var = metrics[pix], spd = metrics[4096 + pix], spl = metrics[8192 + pix];
    for (int j = 0; j < 3; j++) {
      float s = red[j][0] + gw[j * 3075 + 3072] * var + gw[j * 3075 + 3073] * spd
              + gw[j * 3075 + 3074] * spl + gb[j];
      gsh[j] = 1.0f / (1.0f + expf(-s));
    }
  }
  __syncthreads();
  bf16* fb = fused + (long)pix * 3072;
  for (int i = t; i < 3072; i += 256) fb[i] = __float2bfloat16(refbuf[i] * gsh[i >> 10]);
}

// ---------------------------------------------------------------- host ------
extern "C" void kernel_launch(void* const* d_in, const int* in_sizes, int n_in,
                              void* d_out, int out_size, void* d_ws, size_t ws_size,
                              hipStream_t stream) {
  const float* rgb = (const float*)d_in[0];
  const float* dep = (const float*)d_in[1];
  const float* lid = (const float*)d_in[2];
  const float* pw[3] = {(const float*)d_in[3], (const float*)d_in[5], (const float*)d_in[7]};
  const float* pb[3] = {(const float*)d_in[4], (const float*)d_in[6], (const float*)d_in[8]};
  const float* qw = (const float*)d_in[9];  const float* qb = (const float*)d_in[10];
  const float* kw = (const float*)d_in[11]; const float* kb = (const float*)d_in[12];
  const float* vw = (const float*)d_in[13]; const float* vb = (const float*)d_in[14];
  const float* ow = (const float*)d_in[15]; const float* obv = (const float*)d_in[16];
  const float* sew1 = (const float*)d_in[17]; const float* seb1 = (const float*)d_in[18];
  const float* sew2 = (const float*)d_in[19]; const float* seb2 = (const float*)d_in[20];
  const float* gw = (const float*)d_in[21];   const float* gb = (const float*)d_in[22];
  const float* fw = (const float*)d_in[23]; const float* fbias = (const float*)d_in[24];

  const bool wall = ws_size >= (170ull << 20);
  const bool pipe = wall || ws_size >= (116ull << 20);

  char* wp = (char*)d_ws;
  auto carve = [&](size_t bytes) -> char* {
    char* r = wp; wp += (bytes + 255) & ~(size_t)255; return r;
  };
  float* cross = (float*)carve(12L * M1 * 4);    // f32, persists
  short* feat  = (short*)carve(12L * M1 * 2);    // bf16 feats; dead after attn -> fwb
  char*  S     = carve((!wall && pipe ? 43L : 35L) * MB);
  float* metrics = (float*)carve(3L * 4096 * 4);
  float* pooled  = (float*)carve(12L * 1024 * 4);
  float* gvec    = (float*)carve(12L * 1024 * 4);
  short* W = wall ? (short*)carve(24L * M1 * 2) : (short*)0;  // 48 MB weight pool

  // S phase 1 (dead after projections):
  short* rgbT = (short*)S;
  short* depT = (short*)(S + 4L * MB);
  short* lidT = (short*)(S + 6L * MB);
  short* pwb[3] = {(short*)(S + 8L * MB), (short*)(S + 9L * MB), (short*)(S + 9728L * 1024)};
  // S phase 2:
  short* Qi  = (short*)S;                       // 8 MB [4][1024 c][1024 d]
  short* Ki  = (short*)(S + 8L * MB);           // 8 MB
  short* Vi  = (short*)(S + 16L * MB);          // 8 MB [4][1024 d][1024 c]
  short* OAi = (short*)(S + 24L * MB);          // 8 MB
  short *wqb, *wkb, *wvb, *wo0, *wo1, *P;
  if (wall) {
    wqb = wkb = wvb = wo0 = wo1 = (short*)0;    // unused
    P = (short*)(S + 32L * MB);
  } else if (pipe) {
    wqb = (short*)(S + 32L * MB); wkb = (short*)(S + 34L * MB);
    wvb = (short*)(S + 36L * MB); wo0 = (short*)(S + 38L * MB);
    wo1 = (short*)(S + 40L * MB); P   = (short*)(S + 42L * MB);
  } else {
    wqb = (short*)(S + 24L * MB); wkb = (short*)(S + 26L * MB);   // share OA slot
    wvb = (short*)(S + 28L * MB); wo0 = (short*)(S + 32L * MB);
    wo1 = wo0;                    P   = (short*)(S + 34L * MB);
  }
  // S phase 3:
  short* fused = (short*)S;                     // 24 MB
  short* fwb   = feat;                          // 18 MB (feat slot)

  auto G = [&](dim3 grid, GemmP g) { gemm_kernel<<<grid, dim3(256), 0, stream>>>(g); };
  auto G2 = [&](dim3 grid, GemmP g) { gemm256_kernel<<<grid, dim3(512), 0, stream>>>(g); };

  // 0) wall: convert ALL attention weights in one dispatch
  if (wall) {
    Cvt4 c{};
    c.s[0] = qw; c.d[0] = (bf16*)(W + 0L * M1);  c.n[0] = 6L * M1;
    c.s[1] = kw; c.d[1] = (bf16*)(W + 6L * M1);  c.n[1] = 6L * M1;
    c.s[2] = vw; c.d[2] = (bf16*)(W + 12L * M1); c.n[2] = 6L * M1;
    c.s[3] = ow; c.d[3] = (bf16*)(W + 18L * M1); c.n[3] = 6L * M1;
    cvt4_k<<<dim3(6144, 4), dim3(256), 0, stream>>>(c);
  }

  // 1) transpose+convert raw inputs
  trans_k<<<dim3(32, 16, 4), dim3(32, 8), 0, stream>>>(rgb, (bf16*)rgbT, 512, 1024);
  trans_k<<<dim3(32, 8, 4),  dim3(32, 8), 0, stream>>>(dep, (bf16*)depT, 256, 1024);
  trans_k<<<dim3(32, 2, 4),  dim3(32, 8), 0, stream>>>(lid, (bf16*)lidT, 64, 1024);

  // 2) proj weights -> bf16, merged proj GEMM (z=12)
  {
    Cvt4 c{};
    c.s[0] = pw[0]; c.d[0] = (bf16*)pwb[0]; c.n[0] = 1024L * 512;
    c.s[1] = pw[1]; c.d[1] = (bf16*)pwb[1]; c.n[1] = 1024L * 256;
    c.s[2] = pw[2]; c.d[2] = (bf16*)pwb[2]; c.n[2] = 1024L * 64;
    c.s[3] = pw[2]; c.d[3] = (bf16*)pwb[2]; c.n[3] = 0;
    cvt4_k<<<dim3(512, 4), dim3(256), 0, stream>>>(c);

    QkvP q{};
    const int Ks[3] = {512, 256, 64};
    const short* Bts[3] = {rgbT, depT, lidT};
    for (int m = 0; m < 3; m++) {
      q.W[m] = pwb[m]; q.F[m] = Bts[m]; q.C[m] = cross + (long)m * 4 * M1;
      q.bias[m] = pb[m]; q.fl[m] = 1 | 2; q.Kd[m] = Ks[m]; q.ld[m] = Ks[m];
    }
    qkv256_kernel<<<dim3(4, 4, 12), dim3(512), 0, stream>>>(q);
  }

  // 3) l2norm + feat + metrics
  norm_k<<<dim3(12288), dim3(256), 0, stream>>>(cross, (bf16*)feat, metrics);

  // 4) attention blocks
  {
    const int qm[6] = {0, 0, 1, 1, 2, 2};
    const int km[6] = {1, 2, 0, 2, 0, 1};
    for (int i = 0; i < 6; i++) {
      const short *wq_i, *wk_i, *wv_i, *woPrev;
      if (wall) {
        wq_i = W + (long)i * M1; wk_i = W + (long)(6 + i) * M1;
        wv_i = W + (long)(12 + i) * M1; woPrev = W + (long)(18 + i - 1) * M1;
      } else {
        short* woCur = (pipe && (i & 1)) ? wo1 : wo0;
        Cvt4 c{};
        c.s[0] = qw + (long)i * M1; c.d[0] = (bf16*)wqb; c.n[0] = M1;
        c.s[1] = kw + (long)i * M1; c.d[1] = (bf16*)wkb; c.n[1] = M1;
        c.s[2] = vw + (long)i * M1; c.d[2] = (bf16*)wvb; c.n[2] = M1;
        c.s[3] = ow + (long)i * M1; c.d[3] = (bf16*)woCur; c.n[3] = M1;
        cvt4_k<<<dim3(1024, 4), dim3(256), 0, stream>>>(c);
        wq_i = wqb; wk_i = wkb; wv_i = wvb;
        woPrev = (i & 1) ? wo0 : wo1;
      }

      QkvP q{};
      q.W[0] = wq_i; q.F[0] = feat + (long)qm[i] * 4 * M1; q.C[0] = Qi;
      q.bias[0] = qb + i * 1024; q.fl[0] = 0;
      q.W[1] = wk_i; q.F[1] = feat + (long)km[i] * 4 * M1; q.C[1] = Ki;
      q.bias[1] = kb + i * 1024; q.fl[1] = 0;
      q.W[2] = wv_i; q.F[2] = feat + (long)km[i] * 4 * M1; q.C[2] = Vi;
      q.bias[2] = vb + i * 1024; q.fl[2] = 1;
      for (int w = 0; w < 3; w++) { q.Kd[w] = 1024; q.ld[w] = 1024; }
      if (pipe && i > 0) {
        // slot 3 = O-conv of block i-1: cross[qm[i-1]] += Wo[i-1] @ OA
        q.W[3] = woPrev;
        q.F[3] = OAi; q.C[3] = cross + (long)qm[i - 1] * 4 * M1;
        q.bias[3] = obv + (i - 1) * 1024; q.fl[3] = 1 | 2 | 4;
        q.Kd[3] = 1024; q.ld[3] = 1024;
        qkv256_kernel<<<dim3(4, 4, 16), dim3(512), 0, stream>>>(q);
      } else {
        qkv256_kernel<<<dim3(4, 4, 12), dim3(512), 0, stream>>>(q);
      }

      attn_sm_k<<<dim3(32, 4), dim3(256), 0, stream>>>(Qi, Ki, (bf16*)P);

      GemmP pv{}; pv.A = P; pv.B = Vi; pv.C = OAi;
      pv.sA1 = 131072; pv.sA2 = 16384; pv.sB1 = M1; pv.sB2 = 128;
      pv.sC1 = M1; pv.sC2 = 128;
      pv.M = 128; pv.N = 1024; pv.K = 128; pv.lda = 128; pv.ldb = 1024; pv.ldc = 1024;
      pv.Z2 = 8; pv.flags = 1;
      G(dim3(8, 1, 32), pv);

      if (!pipe) {
        GemmP o{}; o.A = wo0; o.B = OAi;
        o.C = cross + (long)qm[i] * 4 * M1; o.bias = obv + i * 1024;
        o.sB1 = M1; o.sC1 = M1;
        o.M = 1024; o.N = 1024; o.K = 1024; o.lda = 1024; o.ldb = 1024; o.ldc = 1024;
        o.Z2 = 1; o.flags = 1 | 2 | 4;
        G(dim3(8, 8, 4), o);       // 128^2 core: 256 blocks = full chip
      }
    }
    if (pipe) {  // trailing O-conv for i=5 -- 128^2 core (256 blocks, full chip)
      GemmP o{}; o.A = wall ? (W + 23L * M1) : wo1; o.B = OAi;
      o.C = cross + (long)qm[5] * 4 * M1; o.bias = obv + 5 * 1024;
      o.sB1 = M1; o.sC1 = M1;
      o.M = 1024; o.N = 1024; o.K = 1024; o.lda = 1024; o.ldb = 1024; o.ldc = 1024;
      o.Z2 = 1; o.flags = 1 | 2 | 4;
      G(dim3(8, 8, 4), o);
    }
  }

  // 5) SE
  zero_k<<<dim3(48), dim3(256), 0, stream>>>(pooled, 12 * 1024);
  pool_k<<<dim3(192), dim3(256), 0, stream>>>(cross, pooled);
  se_k<<<dim3(12), dim3(256), 0, stream>>>(pooled, sew1, seb1, sew2, seb2, gvec);

  // 6) gates + fused
  gatefuse_k<<<dim3(4096), dim3(256), 0, stream>>>(cross, gvec, metrics, gw, gb, (bf16*)fused);

  // 7) fusion conv -> d_out f32; m on blockIdx.x (XCD A-strip, flag 32)
  {
    cvt_k<<<dim3(9216), dim3(256), 0, stream>>>(fw, (bf16*)fwb, 9L * M1);
    GemmP g{}; g.A = fwb; g.B = fused; g.C = d_out; g.bias = fbias;
    g.sB1 = (long)1024 * 3072; g.sC1 = (long)3072 * 1024;
    g.M = 3072; g.N = 1024; g.K = 3072; g.lda = 3072; g.ldb = 3072; g.ldc = 1024;
    g.Z2 = 1; g.flags = 2 | 32;
    G2(dim3(12, 4, 4), g);
  }
  (void)in_sizes; (void)n_in; (void)out_size;
}

// Round 9
// 925.709 us; speedup vs baseline: 1.0386x; 1.0386x over previous
//
#include <hip/hip_runtime.h>
#include <hip/hip_bf16.h>

typedef __attribute__((ext_vector_type(8))) short short8;
typedef __attribute__((ext_vector_type(4))) short short4v;
typedef __attribute__((ext_vector_type(4))) float floatx4;
typedef __hip_bfloat16 bf16;

#define M1 1048576L  // 1024*1024
#define MB (1024L * 1024L)

__device__ __forceinline__ void async16(const short* g, short* l) {
  __builtin_amdgcn_global_load_lds((const __attribute__((address_space(1))) void*)g,
                                   (__attribute__((address_space(3))) void*)l, 16, 0, 0);
}

// ===================== 256x256 8-wave BK=64 core (r9/r10, reverted r12) ======
// r9 measured: fusion 110us, MfmaUtil 27.7%, conflicts 0. r11's 4-sub-phase
// variant REGRESSED (119us, 25%, plus a 19.9ms pathological outlier) -> this
// is the r9/r10 structure verbatim. Known ceiling ~27% (LDS-drain vs MFMA
// time-multiplex); breaking it needs the exact m201 fine-phase schedule.
#define LDS256 16384  // shorts per (buffer x matrix)

__device__ __forceinline__ void gemm256_loop(const short* A, const short* B, int K,
    int lda, int ldb, short* sA, short* sB, int m0, int n0, floatx4 (&acc)[8][4]) {
  const int tid = threadIdx.x, wave = tid >> 6, lane = tid & 63;
  const int lane15 = lane & 15, quad = lane >> 4;
  const int wm = wave & 1, wn = wave >> 1;
  // staging: thread tid covers 16B chunk (tid&7) of row (tid>>3); stored chunk
  // slot p holds logical kchunk p^(row&7) -> pre-swizzled global src (rule #21)
  const int r0t = tid >> 3;                         // 0..63
  const int ksw = ((tid & 7) ^ (r0t & 7)) * 8;      // shorts
  const short* aS = A + (long)(m0 + r0t) * lda + ksw;
  const short* bS = B + (long)(n0 + r0t) * ldb + ksw;
  short* ldA = sA + tid * 8;
  short* ldB = sB + tid * 8;
  // read-side: frag (mt,kk) lane l: row = base + mt*16 + (l&15),
  // kchunk = kk*4 + quad, stored at slot chunk^(row&7) = chunk^(l&7)
  const int pos0 = (quad ^ (lane15 & 7)) * 8;       // shorts, kk=0
  const int aOff = (wm * 128 + lane15) * 64 + pos0;
  const int bOff = (wn * 64 + lane15) * 64 + pos0;  // kk=1: XOR 32 shorts

#pragma unroll
  for (int i = 0; i < 8; i++)
#pragma unroll
    for (int j = 0; j < 4; j++) { floatx4 zz = {0.f, 0.f, 0.f, 0.f}; acc[i][j] = zz; }

  auto stage = [&](int bi, long kOff) {
#pragma unroll
    for (int j = 0; j < 4; ++j)
      async16(aS + kOff + (long)j * 64 * lda, ldA + bi * LDS256 + j * 4096);
#pragma unroll
    for (int j = 0; j < 4; ++j)
      async16(bS + kOff + (long)j * 64 * ldb, ldB + bi * LDS256 + j * 4096);
  };

  stage(0, 0);
  const int NT = K >> 6;
  for (int t = 0; t < NT; ++t) {
    const int bi = t & 1;
    if (t + 1 < NT) {
      stage(bi ^ 1, (long)(t + 1) * 64);
      // wait only for tile t's 8 loads; t+1's 8 stay in flight (T4).
      asm volatile("s_waitcnt vmcnt(8)" ::: "memory");
    } else {
      asm volatile("s_waitcnt vmcnt(0)" ::: "memory");
    }
    __builtin_amdgcn_s_barrier();       // tile-t data ready for all waves
    __builtin_amdgcn_sched_barrier(0);  // pin LDS reads below the barrier
    const short* aB = sA + bi * LDS256;
    const short* bB = sB + bi * LDS256;
    short8 fa[4][2], fb0[2][2], fb1[2][2];
    // P0: A-low + B-low, MFMA quadrant (m-low, n-low)
#pragma unroll
    for (int mh = 0; mh < 4; ++mh)
#pragma unroll
      for (int kk = 0; kk < 2; ++kk)
        fa[mh][kk] = *(const short8*)(aB + ((aOff + mh * 1024) ^ (kk * 32)));
#pragma unroll
    for (int nn = 0; nn < 2; ++nn)
#pragma unroll
      for (int kk = 0; kk < 2; ++kk)
        fb0[nn][kk] = *(const short8*)(bB + ((bOff + nn * 1024) ^ (kk * 32)));
    __builtin_amdgcn_s_setprio(1);
#pragma unroll
    for (int mh = 0; mh < 4; ++mh)
#pragma unroll
      for (int nn = 0; nn < 2; ++nn)
#pragma unroll
        for (int kk = 0; kk < 2; ++kk)
          acc[mh][nn] = __builtin_amdgcn_mfma_f32_16x16x32_bf16(fa[mh][kk], fb0[nn][kk], acc[mh][nn], 0, 0, 0);
    __builtin_amdgcn_s_setprio(0);
    // P1: B-high, MFMA (m-low, n-high)
#pragma unroll
    for (int nn = 0; nn < 2; ++nn)
#pragma unroll
      for (int kk = 0; kk < 2; ++kk)
        fb1[nn][kk] = *(const short8*)(bB + ((bOff + (2 + nn) * 1024) ^ (kk * 32)));
    __builtin_amdgcn_s_setprio(1);
#pragma unroll
    for (int mh = 0; mh < 4; ++mh)
#pragma unroll
      for (int nn = 0; nn < 2; ++nn)
#pragma unroll
        for (int kk = 0; kk < 2; ++kk)
          acc[mh][2 + nn] = __builtin_amdgcn_mfma_f32_16x16x32_bf16(fa[mh][kk], fb1[nn][kk], acc[mh][2 + nn], 0, 0, 0);
    __builtin_amdgcn_s_setprio(0);
    // P2: A-high, MFMA (m-high, n-high)
#pragma unroll
    for (int mh = 0; mh < 4; ++mh)
#pragma unroll
      for (int kk = 0; kk < 2; ++kk)
        fa[mh][kk] = *(const short8*)(aB + ((aOff + (4 + mh) * 1024) ^ (kk * 32)));
    __builtin_amdgcn_s_setprio(1);
#pragma unroll
    for (int mh = 0; mh < 4; ++mh)
#pragma unroll
      for (int nn = 0; nn < 2; ++nn)
#pragma unroll
        for (int kk = 0; kk < 2; ++kk)
          acc[4 + mh][2 + nn] = __builtin_amdgcn_mfma_f32_16x16x32_bf16(fa[mh][kk], fb1[nn][kk], acc[4 + mh][2 + nn], 0, 0, 0);
    __builtin_amdgcn_s_setprio(0);
    // P3: MFMA (m-high, n-low) -- fb0 still live
    __builtin_amdgcn_s_setprio(1);
#pragma unroll
    for (int mh = 0; mh < 4; ++mh)
#pragma unroll
      for (int nn = 0; nn < 2; ++nn)
#pragma unroll
        for (int kk = 0; kk < 2; ++kk)
          acc[4 + mh][nn] = __builtin_amdgcn_mfma_f32_16x16x32_bf16(fa[mh][kk], fb0[nn][kk], acc[4 + mh][nn], 0, 0, 0);
    __builtin_amdgcn_s_setprio(0);
    __builtin_amdgcn_s_barrier();   // reads of buf bi retired -> next stage may overwrite
  }
}

// flags: 1=C^T  2=f32  4=RMW accumulate (f32 C^T)  32=grid xy swapped
__device__ __forceinline__ void epi256(void* C, const float* bias, long cOff,
    int ldc, int fl, int m0, int n0, floatx4 (&acc)[8][4]) {
  const int lane = threadIdx.x & 63, wave = threadIdx.x >> 6;
  const int lane15 = lane & 15, quad = lane >> 4;
  const int wm = wave & 1, wn = wave >> 1;
#pragma unroll
  for (int mt = 0; mt < 8; mt++)
#pragma unroll
    for (int nt = 0; nt < 4; nt++) {
      const int mg = m0 + wm * 128 + mt * 16 + quad * 4;
      const int ng = n0 + wn * 64 + nt * 16 + lane15;
      floatx4 v = acc[mt][nt];
      if (bias) {
        v.x += bias[mg + 0]; v.y += bias[mg + 1];
        v.z += bias[mg + 2]; v.w += bias[mg + 3];
      }
      if (fl & 1) {  // C^T: [N][ldc]
        const long o = cOff + (long)ng * ldc + mg;
        if (fl & 2) {
          float* cp = (float*)C + o;
          if (fl & 4) { v.x += cp[0]; v.y += cp[1]; v.z += cp[2]; v.w += cp[3]; }
          cp[0] = v.x; cp[1] = v.y; cp[2] = v.z; cp[3] = v.w;
        } else {
          bf16* cp = (bf16*)C + o;
          cp[0] = __float2bfloat16(v.x); cp[1] = __float2bfloat16(v.y);
          cp[2] = __float2bfloat16(v.z); cp[3] = __float2bfloat16(v.w);
        }
      } else {       // plain C: [M][ldc]
        const long o = cOff + (long)mg * ldc + ng;
        if (fl & 2) {
          float* cp = (float*)C + o;
          cp[0] = v.x; cp[ldc] = v.y; cp[2L * ldc] = v.z; cp[3L * ldc] = v.w;
        } else {
          bf16* cp = (bf16*)C + o;
          cp[0] = __float2bfloat16(v.x); cp[ldc] = __float2bfloat16(v.y);
          cp[2L * ldc] = __float2bfloat16(v.z); cp[3L * ldc] = __float2bfloat16(v.w);
        }
      }
    }
}

// ------------------------------------------------- generic strided-z GEMM ---
struct GemmP {
  const short* A; const short* B; void* C; const float* bias;
  long sA1, sA2, sB1, sB2, sC1, sC2, sb1, sb2;
  int M, N, K, lda, ldb, ldc, Z2, flags;
};

__global__ __launch_bounds__(512, 2) void gemm256_kernel(GemmP p) {
  __shared__ __align__(16) short sA[2 * LDS256];
  __shared__ __align__(16) short sB[2 * LDS256];
  const int z = blockIdx.z, z1 = z / p.Z2, z2 = z % p.Z2;
  const short* A = p.A + z1 * p.sA1 + z2 * p.sA2;
  const short* B = p.B + z1 * p.sB1 + z2 * p.sB2;
  const long cOff = z1 * p.sC1 + z2 * p.sC2;
  const float* bias = p.bias;
  if (bias) bias += z1 * p.sb1 + z2 * p.sb2;
  int m0, n0;
  if (p.flags & 32) { m0 = blockIdx.x * 256; n0 = blockIdx.y * 256; }
  else              { m0 = blockIdx.y * 256; n0 = blockIdx.x * 256; }
  floatx4 acc[8][4];
  gemm256_loop(A, B, p.K, p.lda, p.ldb, sA, sB, m0, n0, acc);
  epi256(p.C, bias, cOff, p.ldc, p.flags, m0, n0, acc);
}

// -------------------------------- 4-way batched GEMM (proj / QKV [+O]) ------
struct QkvP {
  const short* W[4]; const short* F[4]; void* C[4]; const float* bias[4];
  int fl[4], Kd[4], ld[4];
};

__global__ __launch_bounds__(512, 2) void qkv256_kernel(QkvP q) {
  __shared__ __align__(16) short sA[2 * LDS256];
  __shared__ __align__(16) short sB[2 * LDS256];
  const int z = blockIdx.z, w = z >> 2, b = z & 3;
  const int K = q.Kd[w], ld = q.ld[w];
  const short* A = q.W[w];
  const short* B = q.F[w] + (long)b * 1024 * K;
  floatx4 acc[8][4];
  gemm256_loop(A, B, K, ld, ld, sA, sB, blockIdx.y * 256, blockIdx.x * 256, acc);
  epi256(q.C[w], q.bias[w], (long)b * M1, 1024, q.fl[w], blockIdx.y * 256, blockIdx.x * 256, acc);
}

// ===================== 128x128 4-wave core (PV + O-conv) =====================
__device__ __forceinline__ void gemm_loop(const short* A, const short* B, int K,
    int lda, int ldb, short* sA, short* sB, int m0, int n0, floatx4 (&acc)[4][4]) {
  const int tid = threadIdx.x, wave = tid >> 6, lane = tid & 63;
  const int lane15 = lane & 15, quad = lane >> 4;
  const int mW = (wave & 1) * 64, nW = (wave >> 1) * 64;
  const int row4 = lane >> 2;
  const int kcol = ((lane & 3) ^ ((row4 >> 1) & 3)) * 8;  // swizzled fetch quad
  const int psw = (lane15 >> 1) & 3;                       // read-side swizzle
  const short* aP0 = A + (long)(m0 + wave * 32 + row4) * lda + kcol;
  const short* aP1 = aP0 + (long)16 * lda;
  const short* bP0 = B + (long)(n0 + wave * 32 + row4) * ldb + kcol;
  const short* bP1 = bP0 + (long)16 * ldb;
  short* sAw = sA + wave * 1024;
  short* sBw = sB + wave * 1024;
  const short* rA = sA + (mW + lane15) * 32 + (quad ^ psw) * 8;
  const short* rB = sB + (nW + lane15) * 32 + (quad ^ psw) * 8;
#pragma unroll
  for (int i = 0; i < 4; i++)
#pragma unroll
    for (int j = 0; j < 4; j++) { floatx4 zz = {0.f, 0.f, 0.f, 0.f}; acc[i][j] = zz; }

  async16(aP0, sAw); async16(aP1, sAw + 512);
  async16(bP0, sBw); async16(bP1, sBw + 512);
  aP0 += 32; aP1 += 32; bP0 += 32; bP1 += 32;
  asm volatile("s_waitcnt vmcnt(0)" ::: "memory");
  __builtin_amdgcn_s_barrier();

  int cur = 0;
  const int NT = K >> 5;
  for (int t = 0; t < NT - 1; ++t) {
    const int nxt = cur ^ 4096;
    async16(aP0, sAw + nxt); async16(aP1, sAw + nxt + 512);
    async16(bP0, sBw + nxt); async16(bP1, sBw + nxt + 512);
    aP0 += 32; aP1 += 32; bP0 += 32; bP1 += 32;
    short8 af[4], bfr[4];
#pragma unroll
    for (int mt = 0; mt < 4; mt++) af[mt] = *(const short8*)(rA + cur + mt * 512);
#pragma unroll
    for (int nt = 0; nt < 4; nt++) bfr[nt] = *(const short8*)(rB + cur + nt * 512);
#pragma unroll
    for (int mt = 0; mt < 4; mt++)
#pragma unroll
      for (int nt = 0; nt < 4; nt++)
        acc[mt][nt] = __builtin_amdgcn_mfma_f32_16x16x32_bf16(af[mt], bfr[nt], acc[mt][nt], 0, 0, 0);
    asm volatile("s_waitcnt vmcnt(0)" ::: "memory");
    __builtin_amdgcn_s_barrier();
    cur = nxt;
  }
  {
    short8 af[4], bfr[4];
#pragma unroll
    for (int mt = 0; mt < 4; mt++) af[mt] = *(const short8*)(rA + cur + mt * 512);
#pragma unroll
    for (int nt = 0; nt < 4; nt++) bfr[nt] = *(const short8*)(rB + cur + nt * 512);
#pragma unroll
    for (int mt = 0; mt < 4; mt++)
#pragma unroll
      for (int nt = 0; nt < 4; nt++)
        acc[mt][nt] = __builtin_amdgcn_mfma_f32_16x16x32_bf16(af[mt], bfr[nt], acc[mt][nt], 0, 0, 0);
  }
}

__device__ __forceinline__ void gemm_epi(void* C, const float* bias, long cOff,
    int ldc, int fl, int m0, int n0, floatx4 (&acc)[4][4]) {
  const int lane = threadIdx.x & 63, wave = threadIdx.x >> 6;
  const int lane15 = lane & 15, quad = lane >> 4;
  const int mW = (wave & 1) * 64, nW = (wave >> 1) * 64;
#pragma unroll
  for (int mt = 0; mt < 4; mt++)
#pragma unroll
    for (int nt = 0; nt < 4; nt++) {
      const int mg = m0 + mW + mt * 16 + quad * 4;
      const int ng = n0 + nW + nt * 16 + lane15;
      floatx4 v = acc[mt][nt];
      if (bias) {
        v.x += bias[mg + 0]; v.y += bias[mg + 1];
        v.z += bias[mg + 2]; v.w += bias[mg + 3];
      }
      if (fl & 1) {
        const long o = cOff + (long)ng * ldc + mg;
        if (fl & 2) {
          float* cp = (float*)C + o;
          if (fl & 4) { v.x += cp[0]; v.y += cp[1]; v.z += cp[2]; v.w += cp[3]; }
          cp[0] = v.x; cp[1] = v.y; cp[2] = v.z; cp[3] = v.w;
        } else {
          bf16* cp = (bf16*)C + o;
          cp[0] = __float2bfloat16(v.x); cp[1] = __float2bfloat16(v.y);
          cp[2] = __float2bfloat16(v.z); cp[3] = __float2bfloat16(v.w);
        }
      } else {
        const long o = cOff + (long)mg * ldc + ng;
        if (fl & 2) {
          float* cp = (float*)C + o;
          cp[0] = v.x; cp[ldc] = v.y; cp[2L * ldc] = v.z; cp[3L * ldc] = v.w;
        } else {
          bf16* cp = (bf16*)C + o;
          cp[0] = __float2bfloat16(v.x); cp[ldc] = __float2bfloat16(v.y);
          cp[2L * ldc] = __float2bfloat16(v.z); cp[3L * ldc] = __float2bfloat16(v.w);
        }
      }
    }
}

__global__ __launch_bounds__(256) void gemm_kernel(GemmP p) {
  __shared__ __align__(16) short sA[8192];
  __shared__ __align__(16) short sB[8192];
  const int z = blockIdx.z, z1 = z / p.Z2, z2 = z % p.Z2;
  const short* A = p.A + z1 * p.sA1 + z2 * p.sA2;
  const short* B = p.B + z1 * p.sB1 + z2 * p.sB2;
  const long cOff = z1 * p.sC1 + z2 * p.sC2;
  const float* bias = p.bias;
  if (bias) bias += z1 * p.sb1 + z2 * p.sb2;
  int m0, n0;
  if (p.flags & 32) { m0 = blockIdx.x * 128; n0 = blockIdx.y * 128; }
  else              { m0 = blockIdx.y * 128; n0 = blockIdx.x * 128; }
  floatx4 acc[4][4];
  gemm_loop(A, B, p.K, p.lda, p.ldb, sA, sB, m0, n0, acc);
  gemm_epi(p.C, bias, cOff, p.ldc, p.flags, m0, n0, acc);
}

// ------------- fused scores + softmax, 16-row strips (full-chip, r12) -------
// grid (32, 8): x = (b,h), y = 16-row strip. r11 profile: 128 blocks left half
// the chip idle for 6 dispatches; 256 blocks = full CU coverage. Softmax is
// row-local so strips stay independent. Staging math inherited from the
// proven 32-row kernel's wave-0 path.
__global__ __launch_bounds__(256) void attn_sm_k(const short* Q, const short* Kt, bf16* P) {
  __shared__ __align__(16) short sA[512];
  __shared__ __align__(16) short sB[4096];
  __shared__ short S16[16 * 132];
  const int z = blockIdx.x, b = z >> 3, h = z & 7;
  const int r0 = blockIdx.y * 16;
  const int tid = threadIdx.x, wave = tid >> 6, lane = tid & 63;
  const int lane15 = lane & 15, quad = lane >> 4;
  const int row4 = lane >> 2;
  const int kcol = ((lane & 3) ^ ((row4 >> 1) & 3)) * 8;
  const int psw = (lane15 >> 1) & 3;
  const short* Ab = Q + (long)b * M1 + (long)h * 131072;
  const short* Bb = Kt + (long)b * M1 + (long)h * 131072;
  const short* aP = Ab + (long)(r0 + row4) * 1024 + kcol;            // wave 0
  const short* bP0 = Bb + (long)(wave * 32 + row4) * 1024 + kcol;
  const short* bP1 = bP0 + (long)16 * 1024;
  short* sBw = sB + wave * 1024;
  const short* rA = sA + lane15 * 32 + (quad ^ psw) * 8;
  const short* rB = sB + (wave * 32 + lane15) * 32 + (quad ^ psw) * 8;
  floatx4 acc[2];
#pragma unroll
  for (int j = 0; j < 2; j++) { floatx4 zz = {0.f, 0.f, 0.f, 0.f}; acc[j] = zz; }
  for (int k0 = 0; k0 < 1024; k0 += 32) {
    __syncthreads();
    if (wave == 0) async16(aP, sA);
    async16(bP0, sBw); async16(bP1, sBw + 512);
    aP += 32; bP0 += 32; bP1 += 32;
    __syncthreads();
    short8 af, bfr[2];
    af = *(const short8*)(rA);
    bfr[0] = *(const short8*)(rB);
    bfr[1] = *(const short8*)(rB + 512);
#pragma unroll
    for (int nt = 0; nt < 2; nt++)
      acc[nt] = __builtin_amdgcn_mfma_f32_16x16x32_bf16(af, bfr[nt], acc[nt], 0, 0, 0);
  }
  const float sc = 0.08838834764831845f;   // 128^-0.5
#pragma unroll
  for (int nt = 0; nt < 2; nt++) {
    const int mg = quad * 4, ng = wave * 32 + nt * 16 + lane15;
    floatx4 v = acc[nt];
    *(bf16*)&S16[(mg + 0) * 132 + ng] = __float2bfloat16(v.x * sc);
    *(bf16*)&S16[(mg + 1) * 132 + ng] = __float2bfloat16(v.y * sc);
    *(bf16*)&S16[(mg + 2) * 132 + ng] = __float2bfloat16(v.z * sc);
    *(bf16*)&S16[(mg + 3) * 132 + ng] = __float2bfloat16(v.w * sc);
  }
  __syncthreads();
  bf16* Pb = P + (long)z * 16384 + (long)r0 * 128;
#pragma unroll
  for (int j = 0; j < 4; j++) {
    const int r = wave * 4 + j;
    float a = __bfloat162float(*(bf16*)&S16[r * 132 + lane]);
    float c = __bfloat162float(*(bf16*)&S16[r * 132 + lane + 64]);
    float m = fmaxf(a, c);
    for (int off = 32; off; off >>= 1) m = fmaxf(m, __shfl_xor(m, off));
    float e0 = expf(a - m), e1 = expf(c - m), s = e0 + e1;
    for (int off = 32; off; off >>= 1) s += __shfl_xor(s, off);
    const float inv = 1.0f / s;
    Pb[r * 128 + lane] = __float2bfloat16(e0 * inv);
    Pb[r * 128 + lane + 64] = __float2bfloat16(e1 * inv);
  }
}

// -------------------------------------------------------- f32 -> bf16 -------
__global__ void cvt_k(const float* src, bf16* dst, long n) {
  long i = ((long)blockIdx.x * 256 + threadIdx.x) * 4;
  if (i + 3 < n) {
    float4 v = *(const float4*)(src + i);
    bf16 t[4] = {__float2bfloat16(v.x), __float2bfloat16(v.y),
                 __float2bfloat16(v.z), __float2bfloat16(v.w)};
    *(short4v*)(dst + i) = *(short4v*)t;
  }
}

struct Cvt4 { const float* s[4]; bf16* d[4]; long n[4]; };
__global__ void cvt4_k(Cvt4 c) {
  const int seg = blockIdx.y;
  long i = ((long)blockIdx.x * 256 + threadIdx.x) * 4;
  if (i + 3 < c.n[seg]) {
    float4 v = *(const float4*)(c.s[seg] + i);
    bf16 t[4] = {__float2bfloat16(v.x), __float2bfloat16(v.y),
                 __float2bfloat16(v.z), __float2bfloat16(v.w)};
    *(short4v*)(c.d[seg] + i) = *(short4v*)t;
  }
}

// ------------------------------------------------------------ transpose -----
__global__ void trans_k(const float* in, bf16* out, int C, int D) {
  __shared__ float tile[32][33];
  const int d0 = blockIdx.x * 32, c0 = blockIdx.y * 32, b = blockIdx.z;
  const float* ib = in + (long)b * C * D;
  bf16* ob = out + (long)b * C * D;
  for (int i = threadIdx.y; i < 32; i += 8)
    tile[i][threadIdx.x] = ib[(long)(c0 + i) * D + d0 + threadIdx.x];
  __syncthreads();
  for (int i = threadIdx.y; i < 32; i += 8)
    ob[(long)(d0 + i) * C + c0 + threadIdx.x] = __float2bfloat16(tile[threadIdx.x][i]);
}

// ------------------------------------------------------ l2norm + metrics ----
__global__ __launch_bounds__(256) void norm_k(float* cross, bf16* feat, float* metrics) {
  const int blk = blockIdx.x;     // mod*4096 + pix
  const int mod = blk >> 12;
  float* base = cross + (long)blk * 1024;
  bf16* fb = feat + (long)blk * 1024;
  const int t = threadIdx.x;
  float v[4]; float ssq = 0.f;
#pragma unroll
  for (int j = 0; j < 4; j++) { v[j] = base[t + j * 256]; ssq += v[j] * v[j]; }
  __shared__ float r1[256], r2[256], r3[256];
  __shared__ float sinv;
  r1[t] = ssq; __syncthreads();
  for (int s = 128; s > 0; s >>= 1) { if (t < s) r1[t] += r1[t + s]; __syncthreads(); }
  if (t == 0) sinv = 1.0f / fmaxf(sqrtf(r1[0]), 1e-12f);
  __syncthreads();
  const float invn = sinv;
  float s1 = 0.f, s2 = 0.f, zc = 0.f;
#pragma unroll
  for (int j = 0; j < 4; j++) {
    float x = v[j] * invn; v[j] = x;
    s1 += x; s2 += x * x; if (x == 0.0f) zc += 1.0f;
  }
  r1[t] = s1; r2[t] = s2; r3[t] = zc; __syncthreads();
  for (int s = 128; s > 0; s >>= 1) {
    if (t < s) { r1[t] += r1[t + s]; r2[t] += r2[t + s]; r3[t] += r3[t + s]; }
    __syncthreads();
  }
  if (t == 0) {
    float m = (mod == 0) ? (r2[0] - r1[0] * r1[0] * (1.0f / 1024.f)) * (1.0f / 1023.f)
                         : r3[0] * (1.0f / 1024.f);
    metrics[blk] = m;
  }
#pragma unroll
  for (int j = 0; j < 4; j++) { base[t + j * 256] = v[j]; fb[t + j * 256] = __float2bfloat16(v[j]); }
}

// ----------------------------------------------------------------- SE -------
__global__ void zero_k(float* p, int n) {
  int i = blockIdx.x * 256 + threadIdx.x;
  if (i < n) p[i] = 0.f;
}

__global__ void pool_k(const float* cross, float* pooled) {
  const int blk = blockIdx.x;          // mb*16 + seg, mb = mod*4+b
  const int seg = blk & 15, mb = blk >> 4;
  const float* base = cross + (long)mb * M1 + (long)seg * 64 * 1024;
  float* pout = pooled + (long)mb * 1024;
  for (int c = threadIdx.x; c < 1024; c += 256) {
    float s = 0.f;
    for (int d = 0; d < 64; d++) s += base[(long)d * 1024 + c];
    atomicAdd(&pout[c], s * (1.0f / 1024.0f));
  }
}

__global__ void se_k(const float* pooled, const float* w1, const float* b1,
                     const float* w2, const float* b2, float* gvec) {
  const int mb = blockIdx.x, mod = mb >> 2, t = threadIdx.x;
  __shared__ float ps[1024]; __shared__ float hs[64];
  const float* p = pooled + (long)mb * 1024;
  for (int c = t; c < 1024; c += 256) ps[c] = p[c];
  __syncthreads();
  if (t < 64) {
    const float* wr = w1 + (long)(mod * 64 + t) * 1024;
    float s = 0.f;
    for (int c = 0; c < 1024; c++) s += wr[c] * ps[c];
    s += b1[mod * 64 + t];
    hs[t] = fmaxf(s, 0.f);
  }
  __syncthreads();
  for (int o = t; o < 1024; o += 256) {
    const float* wr = w2 + (long)(mod * 1024 + o) * 64;
    float s = 0.f;
    for (int j = 0; j < 64; j++) s += wr[j] * hs[j];
    s += b2[mod * 1024 + o];
    gvec[(long)mb * 1024 + o] = 1.0f / (1.0f + expf(-s));
  }
}

// ------------------------------------------------------- gates + fused ------
__global__ __launch_bounds__(256) void gatefuse_k(const float* cross, const float* gvec,
    const float* metrics, const float* gw, const float* gb, bf16* fused) {
  const int pix = blockIdx.x;          // b*1024 + d
  const int b = pix >> 10, t = threadIdx.x;
  __shared__ float refbuf[3072];
  __shared__ float red[3][256];
  __shared__ float gsh[3];
  float p0 = 0.f, p1 = 0.f, p2 = 0.f;
  for (int mod = 0; mod < 3; mod++) {
    const float* cb = cross + ((long)mod * 4096 + pix) * 1024;
    const float* gv = gvec + (long)(mod * 4 + b) * 1024;
    for (int c = t; c < 1024; c += 256) {
      float val = cb[c] * gv[c];
      refbuf[mod * 1024 + c] = val;
      p0 += gw[0 * 3075 + mod * 1024 + c] * val;
      p1 += gw[1 * 3075 + mod * 1024 + c] * val;
      p2 += gw[2 * 3075 + mod * 1024 + c] * val;
    }
  }
  red[0][t] = p0; red[1][t] = p1; red[2][t] = p2; __syncthreads();
  for (int s = 128; s > 0; s >>= 1) {
    if (t < s) { red[0][t] += red[0][t + s]; red[1][t] += red[1][t + s]; red[2][t] += red[2][t + s]; }
    __syncthreads();
  }
  if (t == 0) {
    const float var = metrics[pix], spd = metrics[4096 + pix], spl = metrics[8192 + pix];
    for (int j = 0; j < 3; j++) {
      float s = red[j][0] + gw[j * 3075 + 3072] * var + gw[j * 3075 + 3073] * spd
              + gw[j * 3075 + 3074] * spl + gb[j];
      gsh[j] = 1.0f / (1.0f + expf(-s));
    }
  }
  __syncthreads();
  bf16* fb = fused + (long)pix * 3072;
  for (int i = t; i < 3072; i += 256) fb[i] = __float2bfloat16(refbuf[i] * gsh[i >> 10]);
}

// ---------------------------------------------------------------- host ------
extern "C" void kernel_launch(void* const* d_in, const int* in_sizes, int n_in,
                              void* d_out, int out_size, void* d_ws, size_t ws_size,
                              hipStream_t stream) {
  const float* rgb = (const float*)d_in[0];
  const float* dep = (const float*)d_in[1];
  const float* lid = (const float*)d_in[2];
  const float* pw[3] = {(const float*)d_in[3], (const float*)d_in[5], (const float*)d_in[7]};
  const float* pb[3] = {(const float*)d_in[4], (const float*)d_in[6], (const float*)d_in[8]};
  const float* qw = (const float*)d_in[9];  const float* qb = (const float*)d_in[10];
  const float* kw = (const float*)d_in[11]; const float* kb = (const float*)d_in[12];
  const float* vw = (const float*)d_in[13]; const float* vb = (const float*)d_in[14];
  const float* ow = (const float*)d_in[15]; const float* obv = (const float*)d_in[16];
  const float* sew1 = (const float*)d_in[17]; const float* seb1 = (const float*)d_in[18];
  const float* sew2 = (const float*)d_in[19]; const float* seb2 = (const float*)d_in[20];
  const float* gw = (const float*)d_in[21];   const float* gb = (const float*)d_in[22];
  const float* fw = (const float*)d_in[23]; const float* fbias = (const float*)d_in[24];

  const bool wall = ws_size >= (170ull << 20);
  const bool pipe = wall || ws_size >= (116ull << 20);

  char* wp = (char*)d_ws;
  auto carve = [&](size_t bytes) -> char* {
    char* r = wp; wp += (bytes + 255) & ~(size_t)255; return r;
  };
  float* cross = (float*)carve(12L * M1 * 4);    // f32, persists
  short* feat  = (short*)carve(12L * M1 * 2);    // bf16 feats; dead after attn -> fwb
  char*  S     = carve((!wall && pipe ? 43L : 35L) * MB);
  float* metrics = (float*)carve(3L * 4096 * 4);
  float* pooled  = (float*)carve(12L * 1024 * 4);
  float* gvec    = (float*)carve(12L * 1024 * 4);
  short* W = wall ? (short*)carve(24L * M1 * 2) : (short*)0;  // 48 MB weight pool

  // S phase 1 (dead after projections):
  short* rgbT = (short*)S;
  short* depT = (short*)(S + 4L * MB);
  short* lidT = (short*)(S + 6L * MB);
  short* pwb[3] = {(short*)(S + 8L * MB), (short*)(S + 9L * MB), (short*)(S + 9728L * 1024)};
  // S phase 2:
  short* Qi  = (short*)S;                       // 8 MB [4][1024 c][1024 d]
  short* Ki  = (short*)(S + 8L * MB);           // 8 MB
  short* Vi  = (short*)(S + 16L * MB);          // 8 MB [4][1024 d][1024 c]
  short* OAi = (short*)(S + 24L * MB);          // 8 MB
  short *wqb, *wkb, *wvb, *wo0, *wo1, *P;
  if (wall) {
    wqb = wkb = wvb = wo0 = wo1 = (short*)0;    // unused
    P = (short*)(S + 32L * MB);
  } else if (pipe) {
    wqb = (short*)(S + 32L * MB); wkb = (short*)(S + 34L * MB);
    wvb = (short*)(S + 36L * MB); wo0 = (short*)(S + 38L * MB);
    wo1 = (short*)(S + 40L * MB); P   = (short*)(S + 42L * MB);
  } else {
    wqb = (short*)(S + 24L * MB); wkb = (short*)(S + 26L * MB);   // share OA slot
    wvb = (short*)(S + 28L * MB); wo0 = (short*)(S + 32L * MB);
    wo1 = wo0;                    P   = (short*)(S + 34L * MB);
  }
  // S phase 3:
  short* fused = (short*)S;                     // 24 MB
  short* fwb   = feat;                          // 18 MB (feat slot)

  auto G = [&](dim3 grid, GemmP g) { gemm_kernel<<<grid, dim3(256), 0, stream>>>(g); };
  auto G2 = [&](dim3 grid, GemmP g) { gemm256_kernel<<<grid, dim3(512), 0, stream>>>(g); };

  // 0) wall: convert ALL attention weights in one dispatch
  if (wall) {
    Cvt4 c{};
    c.s[0] = qw; c.d[0] = (bf16*)(W + 0L * M1);  c.n[0] = 6L * M1;
    c.s[1] = kw; c.d[1] = (bf16*)(W + 6L * M1);  c.n[1] = 6L * M1;
    c.s[2] = vw; c.d[2] = (bf16*)(W + 12L * M1); c.n[2] = 6L * M1;
    c.s[3] = ow; c.d[3] = (bf16*)(W + 18L * M1); c.n[3] = 6L * M1;
    cvt4_k<<<dim3(6144, 4), dim3(256), 0, stream>>>(c);
  }

  // 1) transpose+convert raw inputs
  trans_k<<<dim3(32, 16, 4), dim3(32, 8), 0, stream>>>(rgb, (bf16*)rgbT, 512, 1024);
  trans_k<<<dim3(32, 8, 4),  dim3(32, 8), 0, stream>>>(dep, (bf16*)depT, 256, 1024);
  trans_k<<<dim3(32, 2, 4),  dim3(32, 8), 0, stream>>>(lid, (bf16*)lidT, 64, 1024);

  // 2) proj weights -> bf16, merged proj GEMM (z=12)
  {
    Cvt4 c{};
    c.s[0] = pw[0]; c.d[0] = (bf16*)pwb[0]; c.n[0] = 1024L * 512;
    c.s[1] = pw[1]; c.d[1] = (bf16*)pwb[1]; c.n[1] = 1024L * 256;
    c.s[2] = pw[2]; c.d[2] = (bf16*)pwb[2]; c.n[2] = 1024L * 64;
    c.s[3] = pw[2]; c.d[3] = (bf16*)pwb[2]; c.n[3] = 0;
    cvt4_k<<<dim3(512, 4), dim3(256), 0, stream>>>(c);

    QkvP q{};
    const int Ks[3] = {512, 256, 64};
    const short* Bts[3] = {rgbT, depT, lidT};
    for (int m = 0; m < 3; m++) {
      q.W[m] = pwb[m]; q.F[m] = Bts[m]; q.C[m] = cross + (long)m * 4 * M1;
      q.bias[m] = pb[m]; q.fl[m] = 1 | 2; q.Kd[m] = Ks[m]; q.ld[m] = Ks[m];
    }
    qkv256_kernel<<<dim3(4, 4, 12), dim3(512), 0, stream>>>(q);
  }

  // 3) l2norm + feat + metrics
  norm_k<<<dim3(12288), dim3(256), 0, stream>>>(cross, (bf16*)feat, metrics);

  // 4) attention blocks
  {
    const int qm[6] = {0, 0, 1, 1, 2, 2};
    const int km[6] = {1, 2, 0, 2, 0, 1};
    for (int i = 0; i < 6; i++) {
      const short *wq_i, *wk_i, *wv_i, *woPrev;
      if (wall) {
        wq_i = W + (long)i * M1; wk_i = W + (long)(6 + i) * M1;
        wv_i = W + (long)(12 + i) * M1; woPrev = W + (long)(18 + i - 1) * M1;
      } else {
        short* woCur = (pipe && (i & 1)) ? wo1 : wo0;
        Cvt4 c{};
        c.s[0] = qw + (long)i * M1; c.d[0] = (bf16*)wqb; c.n[0] = M1;
        c.s[1] = kw + (long)i * M1; c.d[1] = (bf16*)wkb; c.n[1] = M1;
        c.s[2] = vw + (long)i * M1; c.d[2] = (bf16*)wvb; c.n[2] = M1;
        c.s[3] = ow + (long)i * M1; c.d[3] = (bf16*)woCur; c.n[3] = M1;
        cvt4_k<<<dim3(1024, 4), dim3(256), 0, stream>>>(c);
        wq_i = wqb; wk_i = wkb; wv_i = wvb;
        woPrev = (i & 1) ? wo0 : wo1;
      }

      QkvP q{};
      q.W[0] = wq_i; q.F[0] = feat + (long)qm[i] * 4 * M1; q.C[0] = Qi;
      q.bias[0] = qb + i * 1024; q.fl[0] = 0;
      q.W[1] = wk_i; q.F[1] = feat + (long)km[i] * 4 * M1; q.C[1] = Ki;
      q.bias[1] = kb + i * 1024; q.fl[1] = 0;
      q.W[2] = wv_i; q.F[2] = feat + (long)km[i] * 4 * M1; q.C[2] = Vi;
      q.bias[2] = vb + i * 1024; q.fl[2] = 1;
      for (int w = 0; w < 3; w++) { q.Kd[w] = 1024; q.ld[w] = 1024; }
      if (pipe && i > 0) {
        // slot 3 = O-conv of block i-1: cross[qm[i-1]] += Wo[i-1] @ OA
        q.W[3] = woPrev;
        q.F[3] = OAi; q.C[3] = cross + (long)qm[i - 1] * 4 * M1;
        q.bias[3] = obv + (i - 1) * 1024; q.fl[3] = 1 | 2 | 4;
        q.Kd[3] = 1024; q.ld[3] = 1024;
        qkv256_kernel<<<dim3(4, 4, 16), dim3(512), 0, stream>>>(q);
      } else {
        qkv256_kernel<<<dim3(4, 4, 12), dim3(512), 0, stream>>>(q);
      }

      attn_sm_k<<<dim3(32, 8), dim3(256), 0, stream>>>(Qi, Ki, (bf16*)P);

      GemmP pv{}; pv.A = P; pv.B = Vi; pv.C = OAi;
      pv.sA1 = 131072; pv.sA2 = 16384; pv.sB1 = M1; pv.sB2 = 128;
      pv.sC1 = M1; pv.sC2 = 128;
      pv.M = 128; pv.N = 1024; pv.K = 128; pv.lda = 128; pv.ldb = 1024; pv.ldc = 1024;
      pv.Z2 = 8; pv.flags = 1;
      G(dim3(8, 1, 32), pv);

      if (!pipe) {
        GemmP o{}; o.A = wo0; o.B = OAi;
        o.C = cross + (long)qm[i] * 4 * M1; o.bias = obv + i * 1024;
        o.sB1 = M1; o.sC1 = M1;
        o.M = 1024; o.N = 1024; o.K = 1024; o.lda = 1024; o.ldb = 1024; o.ldc = 1024;
        o.Z2 = 1; o.flags = 1 | 2 | 4;
        G(dim3(8, 8, 4), o);       // 128^2 core: 256 blocks = full chip
      }
    }
    if (pipe) {  // trailing O-conv for i=5 -- 128^2 core (256 blocks, full chip)
      GemmP o{}; o.A = wall ? (W + 23L * M1) : wo1; o.B = OAi;
      o.C = cross + (long)qm[5] * 4 * M1; o.bias = obv + 5 * 1024;
      o.sB1 = M1; o.sC1 = M1;
      o.M = 1024; o.N = 1024; o.K = 1024; o.lda = 1024; o.ldb = 1024; o.ldc = 1024;
      o.Z2 = 1; o.flags = 1 | 2 | 4;
      G(dim3(8, 8, 4), o);
    }
  }

  // 5) SE
  zero_k<<<dim3(48), dim3(256), 0, stream>>>(pooled, 12 * 1024);
  pool_k<<<dim3(192), dim3(256), 0, stream>>>(cross, pooled);
  se_k<<<dim3(12), dim3(256), 0, stream>>>(pooled, sew1, seb1, sew2, seb2, gvec);

  // 6) gates + fused
  gatefuse_k<<<dim3(4096), dim3(256), 0, stream>>>(cross, gvec, metrics, gw, gb, (bf16*)fused);

  // 7) fusion conv -> d_out f32; m on blockIdx.x (XCD A-strip, flag 32)
  {
    cvt_k<<<dim3(9216), dim3(256), 0, stream>>>(fw, (bf16*)fwb, 9L * M1);
    GemmP g{}; g.A = fwb; g.B = fused; g.C = d_out; g.bias = fbias;
    g.sB1 = (long)1024 * 3072; g.sC1 = (long)3072 * 1024;
    g.M = 3072; g.N = 1024; g.K = 3072; g.lda = 3072; g.ldb = 3072; g.ldc = 1024;
    g.Z2 = 1; g.flags = 2 | 32;
    G2(dim3(12, 4, 4), g);
  }
  (void)in_sizes; (void)n_in; (void)out_size;
}

// Round 10
// 920.298 us; speedup vs baseline: 1.0447x; 1.0059x over previous
//
#include <hip/hip_runtime.h>
#include <hip/hip_bf16.h>

typedef __attribute__((ext_vector_type(8))) short short8;
typedef __attribute__((ext_vector_type(4))) short short4v;
typedef __attribute__((ext_vector_type(4))) float floatx4;
typedef __hip_bfloat16 bf16;

#define M1 1048576L  // 1024*1024
#define MB (1024L * 1024L)

__device__ __forceinline__ void async16(const short* g, short* l) {
  __builtin_amdgcn_global_load_lds((const __attribute__((address_space(1))) void*)g,
                                   (__attribute__((address_space(3))) void*)l, 16, 0, 0);
}

// r13: XCD-aware bijective blockIdx swizzle (T1, m204 formula). Each XCD gets
// a contiguous chunk of flattened ids -> weight/feature panels L2-resident.
__device__ __forceinline__ void xcd_swz(int& bx, int& by, int& bz) {
  const int nx = gridDim.x, ny = gridDim.y;
  const int nwg = nx * ny * gridDim.z;
  const int lin = blockIdx.x + nx * (blockIdx.y + ny * blockIdx.z);
  const int q = nwg >> 3, r = nwg & 7;
  const int xcd = lin & 7, idx = lin >> 3;
  const int id2 = (xcd < r) ? (xcd * (q + 1) + idx)
                            : (r * (q + 1) + (xcd - r) * q + idx);
  bx = id2 % nx;
  const int t = id2 / nx;
  by = t % ny;
  bz = t / ny;
}

// ===================== 256x256 8-wave BK=64 core (r9 structure) ==============
// r9/r12 measured: fusion 111us, MfmaUtil 27.8%, conflicts 0, VGPR 112+64AGPR
// -> 1 block/CU (register-limited), no inter-block overlap. ~27% is this
// structure's ceiling; breaking it needs the m201 fine-phase geometry.
#define LDS256 16384  // shorts per (buffer x matrix)

__device__ __forceinline__ void gemm256_loop(const short* A, const short* B, int K,
    int lda, int ldb, short* sA, short* sB, int m0, int n0, floatx4 (&acc)[8][4]) {
  const int tid = threadIdx.x, wave = tid >> 6, lane = tid & 63;
  const int lane15 = lane & 15, quad = lane >> 4;
  const int wm = wave & 1, wn = wave >> 1;
  // staging: thread tid covers 16B chunk (tid&7) of row (tid>>3); stored chunk
  // slot p holds logical kchunk p^(row&7) -> pre-swizzled global src (rule #21)
  const int r0t = tid >> 3;                         // 0..63
  const int ksw = ((tid & 7) ^ (r0t & 7)) * 8;      // shorts
  const short* aS = A + (long)(m0 + r0t) * lda + ksw;
  const short* bS = B + (long)(n0 + r0t) * ldb + ksw;
  short* ldA = sA + tid * 8;
  short* ldB = sB + tid * 8;
  // read-side: frag (mt,kk) lane l: row = base + mt*16 + (l&15),
  // kchunk = kk*4 + quad, stored at slot chunk^(row&7) = chunk^(l&7)
  const int pos0 = (quad ^ (lane15 & 7)) * 8;       // shorts, kk=0
  const int aOff = (wm * 128 + lane15) * 64 + pos0;
  const int bOff = (wn * 64 + lane15) * 64 + pos0;  // kk=1: XOR 32 shorts

#pragma unroll
  for (int i = 0; i < 8; i++)
#pragma unroll
    for (int j = 0; j < 4; j++) { floatx4 zz = {0.f, 0.f, 0.f, 0.f}; acc[i][j] = zz; }

  auto stage = [&](int bi, long kOff) {
#pragma unroll
    for (int j = 0; j < 4; ++j)
      async16(aS + kOff + (long)j * 64 * lda, ldA + bi * LDS256 + j * 4096);
#pragma unroll
    for (int j = 0; j < 4; ++j)
      async16(bS + kOff + (long)j * 64 * ldb, ldB + bi * LDS256 + j * 4096);
  };

  stage(0, 0);
  const int NT = K >> 6;
  for (int t = 0; t < NT; ++t) {
    const int bi = t & 1;
    if (t + 1 < NT) {
      stage(bi ^ 1, (long)(t + 1) * 64);
      // wait only for tile t's 8 loads; t+1's 8 stay in flight (T4).
      asm volatile("s_waitcnt vmcnt(8)" ::: "memory");
    } else {
      asm volatile("s_waitcnt vmcnt(0)" ::: "memory");
    }
    __builtin_amdgcn_s_barrier();       // tile-t data ready for all waves
    __builtin_amdgcn_sched_barrier(0);  // pin LDS reads below the barrier
    const short* aB = sA + bi * LDS256;
    const short* bB = sB + bi * LDS256;
    short8 fa[4][2], fb0[2][2], fb1[2][2];
    // P0: A-low + B-low, MFMA quadrant (m-low, n-low)
#pragma unroll
    for (int mh = 0; mh < 4; ++mh)
#pragma unroll
      for (int kk = 0; kk < 2; ++kk)
        fa[mh][kk] = *(const short8*)(aB + ((aOff + mh * 1024) ^ (kk * 32)));
#pragma unroll
    for (int nn = 0; nn < 2; ++nn)
#pragma unroll
      for (int kk = 0; kk < 2; ++kk)
        fb0[nn][kk] = *(const short8*)(bB + ((bOff + nn * 1024) ^ (kk * 32)));
    __builtin_amdgcn_s_setprio(1);
#pragma unroll
    for (int mh = 0; mh < 4; ++mh)
#pragma unroll
      for (int nn = 0; nn < 2; ++nn)
#pragma unroll
        for (int kk = 0; kk < 2; ++kk)
          acc[mh][nn] = __builtin_amdgcn_mfma_f32_16x16x32_bf16(fa[mh][kk], fb0[nn][kk], acc[mh][nn], 0, 0, 0);
    __builtin_amdgcn_s_setprio(0);
    // P1: B-high, MFMA (m-low, n-high)
#pragma unroll
    for (int nn = 0; nn < 2; ++nn)
#pragma unroll
      for (int kk = 0; kk < 2; ++kk)
        fb1[nn][kk] = *(const short8*)(bB + ((bOff + (2 + nn) * 1024) ^ (kk * 32)));
    __builtin_amdgcn_s_setprio(1);
#pragma unroll
    for (int mh = 0; mh < 4; ++mh)
#pragma unroll
      for (int nn = 0; nn < 2; ++nn)
#pragma unroll
        for (int kk = 0; kk < 2; ++kk)
          acc[mh][2 + nn] = __builtin_amdgcn_mfma_f32_16x16x32_bf16(fa[mh][kk], fb1[nn][kk], acc[mh][2 + nn], 0, 0, 0);
    __builtin_amdgcn_s_setprio(0);
    // P2: A-high, MFMA (m-high, n-high)
#pragma unroll
    for (int mh = 0; mh < 4; ++mh)
#pragma unroll
      for (int kk = 0; kk < 2; ++kk)
        fa[mh][kk] = *(const short8*)(aB + ((aOff + (4 + mh) * 1024) ^ (kk * 32)));
    __builtin_amdgcn_s_setprio(1);
#pragma unroll
    for (int mh = 0; mh < 4; ++mh)
#pragma unroll
      for (int nn = 0; nn < 2; ++nn)
#pragma unroll
        for (int kk = 0; kk < 2; ++kk)
          acc[4 + mh][2 + nn] = __builtin_amdgcn_mfma_f32_16x16x32_bf16(fa[mh][kk], fb1[nn][kk], acc[4 + mh][2 + nn], 0, 0, 0);
    __builtin_amdgcn_s_setprio(0);
    // P3: MFMA (m-high, n-low) -- fb0 still live
    __builtin_amdgcn_s_setprio(1);
#pragma unroll
    for (int mh = 0; mh < 4; ++mh)
#pragma unroll
      for (int nn = 0; nn < 2; ++nn)
#pragma unroll
        for (int kk = 0; kk < 2; ++kk)
          acc[4 + mh][nn] = __builtin_amdgcn_mfma_f32_16x16x32_bf16(fa[mh][kk], fb0[nn][kk], acc[4 + mh][nn], 0, 0, 0);
    __builtin_amdgcn_s_setprio(0);
    __builtin_amdgcn_s_barrier();   // reads of buf bi retired -> next stage may overwrite
  }
}

// flags: 1=C^T  2=f32  4=RMW accumulate (f32 C^T)  32=grid xy swapped
__device__ __forceinline__ void epi256(void* C, const float* bias, long cOff,
    int ldc, int fl, int m0, int n0, floatx4 (&acc)[8][4]) {
  const int lane = threadIdx.x & 63, wave = threadIdx.x >> 6;
  const int lane15 = lane & 15, quad = lane >> 4;
  const int wm = wave & 1, wn = wave >> 1;
#pragma unroll
  for (int mt = 0; mt < 8; mt++)
#pragma unroll
    for (int nt = 0; nt < 4; nt++) {
      const int mg = m0 + wm * 128 + mt * 16 + quad * 4;
      const int ng = n0 + wn * 64 + nt * 16 + lane15;
      floatx4 v = acc[mt][nt];
      if (bias) {
        v.x += bias[mg + 0]; v.y += bias[mg + 1];
        v.z += bias[mg + 2]; v.w += bias[mg + 3];
      }
      if (fl & 1) {  // C^T: [N][ldc]
        const long o = cOff + (long)ng * ldc + mg;
        if (fl & 2) {
          float* cp = (float*)C + o;
          if (fl & 4) { v.x += cp[0]; v.y += cp[1]; v.z += cp[2]; v.w += cp[3]; }
          cp[0] = v.x; cp[1] = v.y; cp[2] = v.z; cp[3] = v.w;
        } else {
          bf16* cp = (bf16*)C + o;
          cp[0] = __float2bfloat16(v.x); cp[1] = __float2bfloat16(v.y);
          cp[2] = __float2bfloat16(v.z); cp[3] = __float2bfloat16(v.w);
        }
      } else {       // plain C: [M][ldc]
        const long o = cOff + (long)mg * ldc + ng;
        if (fl & 2) {
          float* cp = (float*)C + o;
          cp[0] = v.x; cp[ldc] = v.y; cp[2L * ldc] = v.z; cp[3L * ldc] = v.w;
        } else {
          bf16* cp = (bf16*)C + o;
          cp[0] = __float2bfloat16(v.x); cp[ldc] = __float2bfloat16(v.y);
          cp[2L * ldc] = __float2bfloat16(v.z); cp[3L * ldc] = __float2bfloat16(v.w);
        }
      }
    }
}

// ------------------------------------------------- generic strided-z GEMM ---
struct GemmP {
  const short* A; const short* B; void* C; const float* bias;
  long sA1, sA2, sB1, sB2, sC1, sC2, sb1, sb2;
  int M, N, K, lda, ldb, ldc, Z2, flags;
};

__global__ __launch_bounds__(512, 2) void gemm256_kernel(GemmP p) {
  __shared__ __align__(16) short sA[2 * LDS256];
  __shared__ __align__(16) short sB[2 * LDS256];
  int bx, by, bz;
  xcd_swz(bx, by, bz);
  const int z = bz, z1 = z / p.Z2, z2 = z % p.Z2;
  const short* A = p.A + z1 * p.sA1 + z2 * p.sA2;
  const short* B = p.B + z1 * p.sB1 + z2 * p.sB2;
  const long cOff = z1 * p.sC1 + z2 * p.sC2;
  const float* bias = p.bias;
  if (bias) bias += z1 * p.sb1 + z2 * p.sb2;
  int m0, n0;
  if (p.flags & 32) { m0 = bx * 256; n0 = by * 256; }
  else              { m0 = by * 256; n0 = bx * 256; }
  floatx4 acc[8][4];
  gemm256_loop(A, B, p.K, p.lda, p.ldb, sA, sB, m0, n0, acc);
  epi256(p.C, bias, cOff, p.ldc, p.flags, m0, n0, acc);
}

// -------------------------------- 4-way batched GEMM (proj / QKV [+O]) ------
struct QkvP {
  const short* W[4]; const short* F[4]; void* C[4]; const float* bias[4];
  int fl[4], Kd[4], ld[4];
};

__global__ __launch_bounds__(512, 2) void qkv256_kernel(QkvP q) {
  __shared__ __align__(16) short sA[2 * LDS256];
  __shared__ __align__(16) short sB[2 * LDS256];
  int bx, by, bz;
  xcd_swz(bx, by, bz);
  const int w = bz >> 2, b = bz & 3;
  const int K = q.Kd[w], ld = q.ld[w];
  const short* A = q.W[w];
  const short* B = q.F[w] + (long)b * 1024 * K;
  floatx4 acc[8][4];
  gemm256_loop(A, B, K, ld, ld, sA, sB, by * 256, bx * 256, acc);
  epi256(q.C[w], q.bias[w], (long)b * M1, 1024, q.fl[w], by * 256, bx * 256, acc);
}

// ===================== 128x128 4-wave core (PV + O-conv) =====================
__device__ __forceinline__ void gemm_loop(const short* A, const short* B, int K,
    int lda, int ldb, short* sA, short* sB, int m0, int n0, floatx4 (&acc)[4][4]) {
  const int tid = threadIdx.x, wave = tid >> 6, lane = tid & 63;
  const int lane15 = lane & 15, quad = lane >> 4;
  const int mW = (wave & 1) * 64, nW = (wave >> 1) * 64;
  const int row4 = lane >> 2;
  const int kcol = ((lane & 3) ^ ((row4 >> 1) & 3)) * 8;  // swizzled fetch quad
  const int psw = (lane15 >> 1) & 3;                       // read-side swizzle
  const short* aP0 = A + (long)(m0 + wave * 32 + row4) * lda + kcol;
  const short* aP1 = aP0 + (long)16 * lda;
  const short* bP0 = B + (long)(n0 + wave * 32 + row4) * ldb + kcol;
  const short* bP1 = bP0 + (long)16 * ldb;
  short* sAw = sA + wave * 1024;
  short* sBw = sB + wave * 1024;
  const short* rA = sA + (mW + lane15) * 32 + (quad ^ psw) * 8;
  const short* rB = sB + (nW + lane15) * 32 + (quad ^ psw) * 8;
#pragma unroll
  for (int i = 0; i < 4; i++)
#pragma unroll
    for (int j = 0; j < 4; j++) { floatx4 zz = {0.f, 0.f, 0.f, 0.f}; acc[i][j] = zz; }

  async16(aP0, sAw); async16(aP1, sAw + 512);
  async16(bP0, sBw); async16(bP1, sBw + 512);
  aP0 += 32; aP1 += 32; bP0 += 32; bP1 += 32;
  asm volatile("s_waitcnt vmcnt(0)" ::: "memory");
  __builtin_amdgcn_s_barrier();

  int cur = 0;
  const int NT = K >> 5;
  for (int t = 0; t < NT - 1; ++t) {
    const int nxt = cur ^ 4096;
    async16(aP0, sAw + nxt); async16(aP1, sAw + nxt + 512);
    async16(bP0, sBw + nxt); async16(bP1, sBw + nxt + 512);
    aP0 += 32; aP1 += 32; bP0 += 32; bP1 += 32;
    short8 af[4], bfr[4];
#pragma unroll
    for (int mt = 0; mt < 4; mt++) af[mt] = *(const short8*)(rA + cur + mt * 512);
#pragma unroll
    for (int nt = 0; nt < 4; nt++) bfr[nt] = *(const short8*)(rB + cur + nt * 512);
#pragma unroll
    for (int mt = 0; mt < 4; mt++)
#pragma unroll
      for (int nt = 0; nt < 4; nt++)
        acc[mt][nt] = __builtin_amdgcn_mfma_f32_16x16x32_bf16(af[mt], bfr[nt], acc[mt][nt], 0, 0, 0);
    asm volatile("s_waitcnt vmcnt(0)" ::: "memory");
    __builtin_amdgcn_s_barrier();
    cur = nxt;
  }
  {
    short8 af[4], bfr[4];
#pragma unroll
    for (int mt = 0; mt < 4; mt++) af[mt] = *(const short8*)(rA + cur + mt * 512);
#pragma unroll
    for (int nt = 0; nt < 4; nt++) bfr[nt] = *(const short8*)(rB + cur + nt * 512);
#pragma unroll
    for (int mt = 0; mt < 4; mt++)
#pragma unroll
      for (int nt = 0; nt < 4; nt++)
        acc[mt][nt] = __builtin_amdgcn_mfma_f32_16x16x32_bf16(af[mt], bfr[nt], acc[mt][nt], 0, 0, 0);
  }
}

__device__ __forceinline__ void gemm_epi(void* C, const float* bias, long cOff,
    int ldc, int fl, int m0, int n0, floatx4 (&acc)[4][4]) {
  const int lane = threadIdx.x & 63, wave = threadIdx.x >> 6;
  const int lane15 = lane & 15, quad = lane >> 4;
  const int mW = (wave & 1) * 64, nW = (wave >> 1) * 64;
#pragma unroll
  for (int mt = 0; mt < 4; mt++)
#pragma unroll
    for (int nt = 0; nt < 4; nt++) {
      const int mg = m0 + mW + mt * 16 + quad * 4;
      const int ng = n0 + nW + nt * 16 + lane15;
      floatx4 v = acc[mt][nt];
      if (bias) {
        v.x += bias[mg + 0]; v.y += bias[mg + 1];
        v.z += bias[mg + 2]; v.w += bias[mg + 3];
      }
      if (fl & 1) {
        const long o = cOff + (long)ng * ldc + mg;
        if (fl & 2) {
          float* cp = (float*)C + o;
          if (fl & 4) { v.x += cp[0]; v.y += cp[1]; v.z += cp[2]; v.w += cp[3]; }
          cp[0] = v.x; cp[1] = v.y; cp[2] = v.z; cp[3] = v.w;
        } else {
          bf16* cp = (bf16*)C + o;
          cp[0] = __float2bfloat16(v.x); cp[1] = __float2bfloat16(v.y);
          cp[2] = __float2bfloat16(v.z); cp[3] = __float2bfloat16(v.w);
        }
      } else {
        const long o = cOff + (long)mg * ldc + ng;
        if (fl & 2) {
          float* cp = (float*)C + o;
          cp[0] = v.x; cp[ldc] = v.y; cp[2L * ldc] = v.z; cp[3L * ldc] = v.w;
        } else {
          bf16* cp = (bf16*)C + o;
          cp[0] = __float2bfloat16(v.x); cp[ldc] = __float2bfloat16(v.y);
          cp[2L * ldc] = __float2bfloat16(v.z); cp[3L * ldc] = __float2bfloat16(v.w);
        }
      }
    }
}

__global__ __launch_bounds__(256) void gemm_kernel(GemmP p) {
  __shared__ __align__(16) short sA[8192];
  __shared__ __align__(16) short sB[8192];
  int bx, by, bz;
  xcd_swz(bx, by, bz);
  const int z = bz, z1 = z / p.Z2, z2 = z % p.Z2;
  const short* A = p.A + z1 * p.sA1 + z2 * p.sA2;
  const short* B = p.B + z1 * p.sB1 + z2 * p.sB2;
  const long cOff = z1 * p.sC1 + z2 * p.sC2;
  const float* bias = p.bias;
  if (bias) bias += z1 * p.sb1 + z2 * p.sb2;
  int m0, n0;
  if (p.flags & 32) { m0 = bx * 128; n0 = by * 128; }
  else              { m0 = by * 128; n0 = bx * 128; }
  floatx4 acc[4][4];
  gemm_loop(A, B, p.K, p.lda, p.ldb, sA, sB, m0, n0, acc);
  gemm_epi(p.C, bias, cOff, p.ldc, p.flags, m0, n0, acc);
}

// ------------- fused scores + softmax, 16-row strips (full-chip, r12) -------
__global__ __launch_bounds__(256) void attn_sm_k(const short* Q, const short* Kt, bf16* P) {
  __shared__ __align__(16) short sA[512];
  __shared__ __align__(16) short sB[4096];
  __shared__ short S16[16 * 132];
  const int z = blockIdx.x, b = z >> 3, h = z & 7;
  const int r0 = blockIdx.y * 16;
  const int tid = threadIdx.x, wave = tid >> 6, lane = tid & 63;
  const int lane15 = lane & 15, quad = lane >> 4;
  const int row4 = lane >> 2;
  const int kcol = ((lane & 3) ^ ((row4 >> 1) & 3)) * 8;
  const int psw = (lane15 >> 1) & 3;
  const short* Ab = Q + (long)b * M1 + (long)h * 131072;
  const short* Bb = Kt + (long)b * M1 + (long)h * 131072;
  const short* aP = Ab + (long)(r0 + row4) * 1024 + kcol;            // wave 0
  const short* bP0 = Bb + (long)(wave * 32 + row4) * 1024 + kcol;
  const short* bP1 = bP0 + (long)16 * 1024;
  short* sBw = sB + wave * 1024;
  const short* rA = sA + lane15 * 32 + (quad ^ psw) * 8;
  const short* rB = sB + (wave * 32 + lane15) * 32 + (quad ^ psw) * 8;
  floatx4 acc[2];
#pragma unroll
  for (int j = 0; j < 2; j++) { floatx4 zz = {0.f, 0.f, 0.f, 0.f}; acc[j] = zz; }
  for (int k0 = 0; k0 < 1024; k0 += 32) {
    __syncthreads();
    if (wave == 0) async16(aP, sA);
    async16(bP0, sBw); async16(bP1, sBw + 512);
    aP += 32; bP0 += 32; bP1 += 32;
    __syncthreads();
    short8 af, bfr[2];
    af = *(const short8*)(rA);
    bfr[0] = *(const short8*)(rB);
    bfr[1] = *(const short8*)(rB + 512);
#pragma unroll
    for (int nt = 0; nt < 2; nt++)
      acc[nt] = __builtin_amdgcn_mfma_f32_16x16x32_bf16(af, bfr[nt], acc[nt], 0, 0, 0);
  }
  const float sc = 0.08838834764831845f;   // 128^-0.5
#pragma unroll
  for (int nt = 0; nt < 2; nt++) {
    const int mg = quad * 4, ng = wave * 32 + nt * 16 + lane15;
    floatx4 v = acc[nt];
    *(bf16*)&S16[(mg + 0) * 132 + ng] = __float2bfloat16(v.x * sc);
    *(bf16*)&S16[(mg + 1) * 132 + ng] = __float2bfloat16(v.y * sc);
    *(bf16*)&S16[(mg + 2) * 132 + ng] = __float2bfloat16(v.z * sc);
    *(bf16*)&S16[(mg + 3) * 132 + ng] = __float2bfloat16(v.w * sc);
  }
  __syncthreads();
  bf16* Pb = P + (long)z * 16384 + (long)r0 * 128;
#pragma unroll
  for (int j = 0; j < 4; j++) {
    const int r = wave * 4 + j;
    float a = __bfloat162float(*(bf16*)&S16[r * 132 + lane]);
    float c = __bfloat162float(*(bf16*)&S16[r * 132 + lane + 64]);
    float m = fmaxf(a, c);
    for (int off = 32; off; off >>= 1) m = fmaxf(m, __shfl_xor(m, off));
    float e0 = expf(a - m), e1 = expf(c - m), s = e0 + e1;
    for (int off = 32; off; off >>= 1) s += __shfl_xor(s, off);
    const float inv = 1.0f / s;
    Pb[r * 128 + lane] = __float2bfloat16(e0 * inv);
    Pb[r * 128 + lane + 64] = __float2bfloat16(e1 * inv);
  }
}

// -------------------------------------------------------- f32 -> bf16 -------
__global__ void cvt_k(const float* src, bf16* dst, long n) {
  long i = ((long)blockIdx.x * 256 + threadIdx.x) * 4;
  if (i + 3 < n) {
    float4 v = *(const float4*)(src + i);
    bf16 t[4] = {__float2bfloat16(v.x), __float2bfloat16(v.y),
                 __float2bfloat16(v.z), __float2bfloat16(v.w)};
    *(short4v*)(dst + i) = *(short4v*)t;
  }
}

struct Cvt4 { const float* s[4]; bf16* d[4]; long n[4]; };
__global__ void cvt4_k(Cvt4 c) {
  const int seg = blockIdx.y;
  long i = ((long)blockIdx.x * 256 + threadIdx.x) * 4;
  if (i + 3 < c.n[seg]) {
    float4 v = *(const float4*)(c.s[seg] + i);
    bf16 t[4] = {__float2bfloat16(v.x), __float2bfloat16(v.y),
                 __float2bfloat16(v.z), __float2bfloat16(v.w)};
    *(short4v*)(c.d[seg] + i) = *(short4v*)t;
  }
}

// ---------------------------------------- transpose (3 modalities merged) ---
struct Tr3 { const float* s[3]; bf16* d[3]; };
__global__ void trans3_k(Tr3 p) {
  __shared__ float tile[32][33];
  const int y = blockIdx.y;
  int mod, c0;
  if (y < 16)      { mod = 0; c0 = y * 32; }
  else if (y < 24) { mod = 1; c0 = (y - 16) * 32; }
  else             { mod = 2; c0 = (y - 24) * 32; }
  const int C = (mod == 0) ? 512 : (mod == 1 ? 256 : 64);
  const int D = 1024;
  const int d0 = blockIdx.x * 32, b = blockIdx.z;
  const float* ib = p.s[mod] + (long)b * C * D;
  bf16* ob = p.d[mod] + (long)b * C * D;
  for (int i = threadIdx.y; i < 32; i += 8)
    tile[i][threadIdx.x] = ib[(long)(c0 + i) * D + d0 + threadIdx.x];
  __syncthreads();
  for (int i = threadIdx.y; i < 32; i += 8)
    ob[(long)(d0 + i) * C + c0 + threadIdx.x] = __float2bfloat16(tile[threadIdx.x][i]);
}

// ------------------------------------------------------ l2norm + metrics ----
__global__ __launch_bounds__(256) void norm_k(float* cross, bf16* feat, float* metrics) {
  const int blk = blockIdx.x;     // mod*4096 + pix
  const int mod = blk >> 12;
  float* base = cross + (long)blk * 1024;
  bf16* fb = feat + (long)blk * 1024;
  const int t = threadIdx.x;
  float v[4]; float ssq = 0.f;
#pragma unroll
  for (int j = 0; j < 4; j++) { v[j] = base[t + j * 256]; ssq += v[j] * v[j]; }
  __shared__ float r1[256], r2[256], r3[256];
  __shared__ float sinv;
  r1[t] = ssq; __syncthreads();
  for (int s = 128; s > 0; s >>= 1) { if (t < s) r1[t] += r1[t + s]; __syncthreads(); }
  if (t == 0) sinv = 1.0f / fmaxf(sqrtf(r1[0]), 1e-12f);
  __syncthreads();
  const float invn = sinv;
  float s1 = 0.f, s2 = 0.f, zc = 0.f;
#pragma unroll
  for (int j = 0; j < 4; j++) {
    float x = v[j] * invn; v[j] = x;
    s1 += x; s2 += x * x; if (x == 0.0f) zc += 1.0f;
  }
  r1[t] = s1; r2[t] = s2; r3[t] = zc; __syncthreads();
  for (int s = 128; s > 0; s >>= 1) {
    if (t < s) { r1[t] += r1[t + s]; r2[t] += r2[t + s]; r3[t] += r3[t + s]; }
    __syncthreads();
  }
  if (t == 0) {
    float m = (mod == 0) ? (r2[0] - r1[0] * r1[0] * (1.0f / 1024.f)) * (1.0f / 1023.f)
                         : r3[0] * (1.0f / 1024.f);
    metrics[blk] = m;
  }
#pragma unroll
  for (int j = 0; j < 4; j++) { base[t + j * 256] = v[j]; fb[t + j * 256] = __float2bfloat16(v[j]); }
}

// ----------------------------------------------------------------- SE -------
__global__ void zero_k(float* p, int n) {
  int i = blockIdx.x * 256 + threadIdx.x;
  if (i < n) p[i] = 0.f;
}

__global__ void pool_k(const float* cross, float* pooled) {
  const int blk = blockIdx.x;          // mb*16 + seg, mb = mod*4+b
  const int seg = blk & 15, mb = blk >> 4;
  const float* base = cross + (long)mb * M1 + (long)seg * 64 * 1024;
  float* pout = pooled + (long)mb * 1024;
  for (int c = threadIdx.x; c < 1024; c += 256) {
    float s = 0.f;
    for (int d = 0; d < 64; d++) s += base[(long)d * 1024 + c];
    atomicAdd(&pout[c], s * (1.0f / 1024.0f));
  }
}

__global__ void se_k(const float* pooled, const float* w1, const float* b1,
                     const float* w2, const float* b2, float* gvec) {
  const int mb = blockIdx.x, mod = mb >> 2, t = threadIdx.x;
  __shared__ float ps[1024]; __shared__ float hs[64];
  const float* p = pooled + (long)mb * 1024;
  for (int c = t; c < 1024; c += 256) ps[c] = p[c];
  __syncthreads();
  if (t < 64) {
    const float* wr = w1 + (long)(mod * 64 + t) * 1024;
    float s = 0.f;
    for (int c = 0; c < 1024; c++) s += wr[c] * ps[c];
    s += b1[mod * 64 + t];
    hs[t] = fmaxf(s, 0.f);
  }
  __syncthreads();
  for (int o = t; o < 1024; o += 256) {
    const float* wr = w2 + (long)(mod * 1024 + o) * 64;
    float s = 0.f;
    for (int j = 0; j < 64; j++) s += wr[j] * hs[j];
    s += b2[mod * 1024 + o];
    gvec[(long)mb * 1024 + o] = 1.0f / (1.0f + expf(-s));
  }
}

// ------------------------------------------------------- gates + fused ------
__global__ __launch_bounds__(256) void gatefuse_k(const float* cross, const float* gvec,
    const float* metrics, const float* gw, const float* gb, bf16* fused) {
  const int pix = blockIdx.x;          // b*1024 + d
  const int b = pix >> 10, t = threadIdx.x;
  __shared__ float refbuf[3072];
  __shared__ float red[3][256];
  __shared__ float gsh[3];
  float p0 = 0.f, p1 = 0.f, p2 = 0.f;
  for (int mod = 0; mod < 3; mod++) {
    const float* cb = cross + ((long)mod * 4096 + pix) * 1024;
    const float* gv = gvec + (long)(mod * 4 + b) * 1024;
    for (int c = t; c < 1024; c += 256) {
      float val = cb[c] * gv[c];
      refbuf[mod * 1024 + c] = val;
      p0 += gw[0 * 3075 + mod * 1024 + c] * val;
      p1 += gw[1 * 3075 + mod * 1024 + c] * val;
      p2 += gw[2 * 3075 + mod * 1024 + c] * val;
    }
  }
  red[0][t] = p0; red[1][t] = p1; red[2][t] = p2; __syncthreads();
  for (int s = 128; s > 0; s >>= 1) {
    if (t < s) { red[0][t] += red[0][t + s]; red[1][t] += red[1][t + s]; red[2][t] += red[2][t + s]; }
    __syncthreads();
  }
  if (t == 0) {
    const float var = metrics[pix], spd = metrics[4096 + pix], spl = metrics[8192 + pix];
    for (int j = 0; j < 3; j++) {
      float s = red[j][0] + gw[j * 3075 + 3072] * var + gw[j * 3075 + 3073] * spd
              + gw[j * 3075 + 3074] * spl + gb[j];
      gsh[j] = 1.0f / (1.0f + expf(-s));
    }
  }
  __syncthreads();
  bf16* fb = fused + (long)pix * 3072;
  for (int i = t; i < 3072; i += 256) fb[i] = __float2bfloat16(refbuf[i] * gsh[i >> 10]);
}

// ---------------------------------------------------------------- host ------
extern "C" void kernel_launch(void* const* d_in, const int* in_sizes, int n_in,
                              void* d_out, int out_size, void* d_ws, size_t ws_size,
                              hipStream_t stream) {
  const float* rgb = (const float*)d_in[0];
  const float* dep = (const float*)d_in[1];
  const float* lid = (const float*)d_in[2];
  const float* pw[3] = {(const float*)d_in[3], (const float*)d_in[5], (const float*)d_in[7]};
  const float* pb[3] = {(const float*)d_in[4], (const float*)d_in[6], (const float*)d_in[8]};
  const float* qw = (const float*)d_in[9];  const float* qb = (const float*)d_in[10];
  const float* kw = (const float*)d_in[11]; const float* kb = (const float*)d_in[12];
  const float* vw = (const float*)d_in[13]; const float* vb = (const float*)d_in[14];
  const float* ow = (const float*)d_in[15]; const float* obv = (const float*)d_in[16];
  const float* sew1 = (const float*)d_in[17]; const float* seb1 = (const float*)d_in[18];
  const float* sew2 = (const float*)d_in[19]; const float* seb2 = (const float*)d_in[20];
  const float* gw = (const float*)d_in[21];   const float* gb = (const float*)d_in[22];
  const float* fw = (const float*)d_in[23]; const float* fbias = (const float*)d_in[24];

  const bool wall = ws_size >= (170ull << 20);
  const bool pipe = wall || ws_size >= (116ull << 20);

  char* wp = (char*)d_ws;
  auto carve = [&](size_t bytes) -> char* {
    char* r = wp; wp += (bytes + 255) & ~(size_t)255; return r;
  };
  float* cross = (float*)carve(12L * M1 * 4);    // f32, persists
  short* feat  = (short*)carve(12L * M1 * 2);    // bf16 feats; dead after attn -> fwb
  char*  S     = carve((!wall && pipe ? 43L : 35L) * MB);
  float* metrics = (float*)carve(3L * 4096 * 4);
  float* pooled  = (float*)carve(12L * 1024 * 4);
  float* gvec    = (float*)carve(12L * 1024 * 4);
  short* W = wall ? (short*)carve(24L * M1 * 2) : (short*)0;  // 48 MB weight pool

  // S phase 1 (dead after projections):
  short* rgbT = (short*)S;
  short* depT = (short*)(S + 4L * MB);
  short* lidT = (short*)(S + 6L * MB);
  short* pwb[3] = {(short*)(S + 8L * MB), (short*)(S + 9L * MB), (short*)(S + 9728L * 1024)};
  // S phase 2:
  short* Qi  = (short*)S;                       // 8 MB [4][1024 c][1024 d]
  short* Ki  = (short*)(S + 8L * MB);           // 8 MB
  short* Vi  = (short*)(S + 16L * MB);          // 8 MB [4][1024 d][1024 c]
  short* OAi = (short*)(S + 24L * MB);          // 8 MB
  short *wqb, *wkb, *wvb, *wo0, *wo1, *P;
  if (wall) {
    wqb = wkb = wvb = wo0 = wo1 = (short*)0;    // unused
    P = (short*)(S + 32L * MB);
  } else if (pipe) {
    wqb = (short*)(S + 32L * MB); wkb = (short*)(S + 34L * MB);
    wvb = (short*)(S + 36L * MB); wo0 = (short*)(S + 38L * MB);
    wo1 = (short*)(S + 40L * MB); P   = (short*)(S + 42L * MB);
  } else {
    wqb = (short*)(S + 24L * MB); wkb = (short*)(S + 26L * MB);   // share OA slot
    wvb = (short*)(S + 28L * MB); wo0 = (short*)(S + 32L * MB);
    wo1 = wo0;                    P   = (short*)(S + 34L * MB);
  }
  // S phase 3:
  short* fused = (short*)S;                     // 24 MB
  short* fwb   = feat;                          // 18 MB (feat slot)

  auto G = [&](dim3 grid, GemmP g) { gemm_kernel<<<grid, dim3(256), 0, stream>>>(g); };
  auto G2 = [&](dim3 grid, GemmP g) { gemm256_kernel<<<grid, dim3(512), 0, stream>>>(g); };

  // 0) wall: convert ALL attention weights in one dispatch
  if (wall) {
    Cvt4 c{};
    c.s[0] = qw; c.d[0] = (bf16*)(W + 0L * M1);  c.n[0] = 6L * M1;
    c.s[1] = kw; c.d[1] = (bf16*)(W + 6L * M1);  c.n[1] = 6L * M1;
    c.s[2] = vw; c.d[2] = (bf16*)(W + 12L * M1); c.n[2] = 6L * M1;
    c.s[3] = ow; c.d[3] = (bf16*)(W + 18L * M1); c.n[3] = 6L * M1;
    cvt4_k<<<dim3(6144, 4), dim3(256), 0, stream>>>(c);
  }

  // 1) transpose+convert raw inputs (merged into one dispatch)
  {
    Tr3 t{};
    t.s[0] = rgb; t.d[0] = (bf16*)rgbT;
    t.s[1] = dep; t.d[1] = (bf16*)depT;
    t.s[2] = lid; t.d[2] = (bf16*)lidT;
    trans3_k<<<dim3(32, 26, 4), dim3(32, 8), 0, stream>>>(t);
  }

  // 2) proj weights -> bf16, merged proj GEMM (z=12)
  {
    Cvt4 c{};
    c.s[0] = pw[0]; c.d[0] = (bf16*)pwb[0]; c.n[0] = 1024L * 512;
    c.s[1] = pw[1]; c.d[1] = (bf16*)pwb[1]; c.n[1] = 1024L * 256;
    c.s[2] = pw[2]; c.d[2] = (bf16*)pwb[2]; c.n[2] = 1024L * 64;
    c.s[3] = pw[2]; c.d[3] = (bf16*)pwb[2]; c.n[3] = 0;
    cvt4_k<<<dim3(512, 4), dim3(256), 0, stream>>>(c);

    QkvP q{};
    const int Ks[3] = {512, 256, 64};
    const short* Bts[3] = {rgbT, depT, lidT};
    for (int m = 0; m < 3; m++) {
      q.W[m] = pwb[m]; q.F[m] = Bts[m]; q.C[m] = cross + (long)m * 4 * M1;
      q.bias[m] = pb[m]; q.fl[m] = 1 | 2; q.Kd[m] = Ks[m]; q.ld[m] = Ks[m];
    }
    qkv256_kernel<<<dim3(4, 4, 12), dim3(512), 0, stream>>>(q);
  }

  // 3) l2norm + feat + metrics
  norm_k<<<dim3(12288), dim3(256), 0, stream>>>(cross, (bf16*)feat, metrics);

  // 4) attention blocks
  {
    const int qm[6] = {0, 0, 1, 1, 2, 2};
    const int km[6] = {1, 2, 0, 2, 0, 1};
    for (int i = 0; i < 6; i++) {
      const short *wq_i, *wk_i, *wv_i, *woPrev;
      if (wall) {
        wq_i = W + (long)i * M1; wk_i = W + (long)(6 + i) * M1;
        wv_i = W + (long)(12 + i) * M1; woPrev = W + (long)(18 + i - 1) * M1;
      } else {
        short* woCur = (pipe && (i & 1)) ? wo1 : wo0;
        Cvt4 c{};
        c.s[0] = qw + (long)i * M1; c.d[0] = (bf16*)wqb; c.n[0] = M1;
        c.s[1] = kw + (long)i * M1; c.d[1] = (bf16*)wkb; c.n[1] = M1;
        c.s[2] = vw + (long)i * M1; c.d[2] = (bf16*)wvb; c.n[2] = M1;
        c.s[3] = ow + (long)i * M1; c.d[3] = (bf16*)woCur; c.n[3] = M1;
        cvt4_k<<<dim3(1024, 4), dim3(256), 0, stream>>>(c);
        wq_i = wqb; wk_i = wkb; wv_i = wvb;
        woPrev = (i & 1) ? wo0 : wo1;
      }

      QkvP q{};
      q.W[0] = wq_i; q.F[0] = feat + (long)qm[i] * 4 * M1; q.C[0] = Qi;
      q.bias[0] = qb + i * 1024; q.fl[0] = 0;
      q.W[1] = wk_i; q.F[1] = feat + (long)km[i] * 4 * M1; q.C[1] = Ki;
      q.bias[1] = kb + i * 1024; q.fl[1] = 0;
      q.W[2] = wv_i; q.F[2] = feat + (long)km[i] * 4 * M1; q.C[2] = Vi;
      q.bias[2] = vb + i * 1024; q.fl[2] = 1;
      for (int w = 0; w < 3; w++) { q.Kd[w] = 1024; q.ld[w] = 1024; }
      if (pipe && i > 0) {
        // slot 3 = O-conv of block i-1: cross[qm[i-1]] += Wo[i-1] @ OA
        q.W[3] = woPrev;
        q.F[3] = OAi; q.C[3] = cross + (long)qm[i - 1] * 4 * M1;
        q.bias[3] = obv + (i - 1) * 1024; q.fl[3] = 1 | 2 | 4;
        q.Kd[3] = 1024; q.ld[3] = 1024;
        qkv256_kernel<<<dim3(4, 4, 16), dim3(512), 0, stream>>>(q);
      } else {
        qkv256_kernel<<<dim3(4, 4, 12), dim3(512), 0, stream>>>(q);
      }

      attn_sm_k<<<dim3(32, 8), dim3(256), 0, stream>>>(Qi, Ki, (bf16*)P);

      GemmP pv{}; pv.A = P; pv.B = Vi; pv.C = OAi;
      pv.sA1 = 131072; pv.sA2 = 16384; pv.sB1 = M1; pv.sB2 = 128;
      pv.sC1 = M1; pv.sC2 = 128;
      pv.M = 128; pv.N = 1024; pv.K = 128; pv.lda = 128; pv.ldb = 1024; pv.ldc = 1024;
      pv.Z2 = 8; pv.flags = 1;
      G(dim3(8, 1, 32), pv);

      if (!pipe) {
        GemmP o{}; o.A = wo0; o.B = OAi;
        o.C = cross + (long)qm[i] * 4 * M1; o.bias = obv + i * 1024;
        o.sB1 = M1; o.sC1 = M1;
        o.M = 1024; o.N = 1024; o.K = 1024; o.lda = 1024; o.ldb = 1024; o.ldc = 1024;
        o.Z2 = 1; o.flags = 1 | 2 | 4;
        G(dim3(8, 8, 4), o);       // 128^2 core: 256 blocks = full chip
      }
    }
    if (pipe) {  // trailing O-conv for i=5 -- 128^2 core (256 blocks, full chip)
      GemmP o{}; o.A = wall ? (W + 23L * M1) : wo1; o.B = OAi;
      o.C = cross + (long)qm[5] * 4 * M1; o.bias = obv + 5 * 1024;
      o.sB1 = M1; o.sC1 = M1;
      o.M = 1024; o.N = 1024; o.K = 1024; o.lda = 1024; o.ldb = 1024; o.ldc = 1024;
      o.Z2 = 1; o.flags = 1 | 2 | 4;
      G(dim3(8, 8, 4), o);
    }
  }

  // 5) SE
  zero_k<<<dim3(48), dim3(256), 0, stream>>>(pooled, 12 * 1024);
  pool_k<<<dim3(192), dim3(256), 0, stream>>>(cross, pooled);
  se_k<<<dim3(12), dim3(256), 0, stream>>>(pooled, sew1, seb1, sew2, seb2, gvec);

  // 6) gates + fused
  gatefuse_k<<<dim3(4096), dim3(256), 0, stream>>>(cross, gvec, metrics, gw, gb, (bf16*)fused);

  // 7) fusion conv -> d_out f32; m on blockIdx.x (XCD A-strip, flag 32)
  {
    cvt_k<<<dim3(9216), dim3(256), 0, stream>>>(fw, (bf16*)fwb, 9L * M1);
    GemmP g{}; g.A = fwb; g.B = fused; g.C = d_out; g.bias = fbias;
    g.sB1 = (long)1024 * 3072; g.sC1 = (long)3072 * 1024;
    g.M = 3072; g.N = 1024; g.K = 3072; g.lda = 3072; g.ldb = 3072; g.ldc = 1024;
    g.Z2 = 1; g.flags = 2 | 32;
    G2(dim3(12, 4, 4), g);
  }
  (void)in_sizes; (void)n_in; (void)out_size;
}